// Round 1
// baseline (1841.019 us; speedup 1.0000x reference)
//
#include <hip/hip_runtime.h>

// Problem constants (MAMGCN submodule): B=16, N=1024, F_IN=64, T=12, K=3, F_OUT=64
#define Bn 16
#define Nn 1024
#define Fn 64
#define Tn 12
#define Kn 3
#define On 64
#define CT 768   // F*T == O*T (flattened trailing dims)

// ---------------------------------------------------------------------------
// K1: lhs[b,n,t'] = sum_f (sum_t x[b,n,f,t]*W1[t]) * W2[f,t']
//     rhs[b,n,t]  = sum_f W3[f]*x[b,n,f,t]
// One wave per (b,n) row; lane = f. Memory-bound on x (50 MB).
// ---------------------------------------------------------------------------
__global__ __launch_bounds__(256) void k_attn_lr(
    const float* __restrict__ x, const float* __restrict__ W1,
    const float* __restrict__ W2, const float* __restrict__ W3,
    float* __restrict__ lhs, float* __restrict__ rhs)
{
  int bn   = blockIdx.x * 4 + (threadIdx.x >> 6);  // (b*N + n)
  int lane = threadIdx.x & 63;                     // = f
  const float* xp = x + (size_t)bn * (Fn * Tn) + lane * Tn;
  float4 v0 = *(const float4*)(xp);
  float4 v1 = *(const float4*)(xp + 4);
  float4 v2 = *(const float4*)(xp + 8);
  float xv[12] = {v0.x, v0.y, v0.z, v0.w, v1.x, v1.y, v1.z, v1.w,
                  v2.x, v2.y, v2.z, v2.w};
  float w3 = W3[lane];
  float tmp = 0.f;
#pragma unroll
  for (int t = 0; t < 12; ++t) tmp += xv[t] * W1[t];
#pragma unroll
  for (int t = 0; t < 12; ++t) {
    float v = tmp * W2[lane * 12 + t];
    float r = w3 * xv[t];
#pragma unroll
    for (int off = 32; off; off >>= 1) {
      v += __shfl_xor(v, off);
      r += __shfl_xor(r, off);
    }
    if (lane == t) {
      lhs[(size_t)bn * 12 + t] = v;
      rhs[(size_t)bn * 12 + t] = r;
    }
  }
}

// ---------------------------------------------------------------------------
// K2: P[b,i,j] = sigmoid( sum_t lhs[b,i,t]*rhs[b,j,t] + bs[i,j] )
// One thread per 4 j's (float4 output). rhs rows are tiny -> L2 resident.
// ---------------------------------------------------------------------------
__global__ __launch_bounds__(256) void k_prod_sig(
    const float* __restrict__ lhs, const float* __restrict__ rhs,
    const float* __restrict__ bs, float* __restrict__ P)
{
  size_t gid = (size_t)blockIdx.x * 256 + threadIdx.x;
  int jc    = (int)(gid % (Nn / 4));
  size_t bi = gid / (Nn / 4);   // b*N + i
  int i     = (int)(bi % Nn);
  size_t b  = bi / Nn;

  const float* lp = lhs + bi * 12;
  float4 l0 = *(const float4*)lp;
  float4 l1 = *(const float4*)(lp + 4);
  float4 l2 = *(const float4*)(lp + 8);
  float l[12] = {l0.x, l0.y, l0.z, l0.w, l1.x, l1.y, l1.z, l1.w,
                 l2.x, l2.y, l2.z, l2.w};
  float4 bsv = *(const float4*)(bs + (size_t)i * Nn + jc * 4);
  float bb[4] = {bsv.x, bsv.y, bsv.z, bsv.w};
  float res[4];
#pragma unroll
  for (int jj = 0; jj < 4; ++jj) {
    const float* rp = rhs + (b * Nn + (size_t)jc * 4 + jj) * 12;
    float4 r0 = *(const float4*)rp;
    float4 r1 = *(const float4*)(rp + 4);
    float4 r2 = *(const float4*)(rp + 8);
    float rr[12] = {r0.x, r0.y, r0.z, r0.w, r1.x, r1.y, r1.z, r1.w,
                    r2.x, r2.y, r2.z, r2.w};
    float d = 0.f;
#pragma unroll
    for (int t = 0; t < 12; ++t) d += l[t] * rr[t];
    d += bb[jj];
    res[jj] = 1.f / (1.f + __expf(-d));
  }
  *(float4*)(P + bi * Nn + (size_t)jc * 4) =
      make_float4(res[0], res[1], res[2], res[3]);
}

// ---------------------------------------------------------------------------
// K3: Sp[b,n,c] = sum_m Vs[n,m] * P[b,m,c]   (batched 1024^3 fp32 GEMM)
// 128x128 tile, BK=8, 256 threads, 8x8 per thread.
// ---------------------------------------------------------------------------
__global__ __launch_bounds__(256) void k_gemm_vs(
    const float* __restrict__ Vs, const float* __restrict__ P,
    float* __restrict__ Sp)
{
  __shared__ float As[8][132];
  __shared__ float Bsh[8][132];
  int tid = threadIdx.x;
  int b   = blockIdx.z;
  int n0  = blockIdx.y * 128;
  int c0  = blockIdx.x * 128;
  const float* Bp = P + (size_t)b * Nn * Nn;
  float acc[8][8] = {};
  int tm = (tid >> 4) * 8, tn = (tid & 15) * 8;
  int arow = tid >> 1, ak = (tid & 1) * 4;      // A: 128 rows(n) x 8 k(m)
  int bk = tid >> 5, bc = (tid & 31) * 4;       // B: 8 rows(m) x 128 cols

  for (int k0 = 0; k0 < Nn; k0 += 8) {
    float4 av = *(const float4*)(Vs + (size_t)(n0 + arow) * Nn + k0 + ak);
    float4 bv = *(const float4*)(Bp + (size_t)(k0 + bk) * Nn + c0 + bc);
    __syncthreads();
    As[ak + 0][arow] = av.x;
    As[ak + 1][arow] = av.y;
    As[ak + 2][arow] = av.z;
    As[ak + 3][arow] = av.w;
    *(float4*)&Bsh[bk][bc] = bv;
    __syncthreads();
#pragma unroll
    for (int kk = 0; kk < 8; ++kk) {
      float a[8], bb[8];
      *(float4*)(a)      = *(const float4*)&As[kk][tm];
      *(float4*)(a + 4)  = *(const float4*)&As[kk][tm + 4];
      *(float4*)(bb)     = *(const float4*)&Bsh[kk][tn];
      *(float4*)(bb + 4) = *(const float4*)&Bsh[kk][tn + 4];
#pragma unroll
      for (int i = 0; i < 8; ++i)
#pragma unroll
        for (int j = 0; j < 8; ++j) acc[i][j] += a[i] * bb[j];
    }
  }
  float* op = Sp + (size_t)b * Nn * Nn;
#pragma unroll
  for (int i = 0; i < 8; ++i) {
    *(float4*)(op + (size_t)(n0 + tm + i) * Nn + c0 + tn)     = *(float4*)&acc[i][0];
    *(float4*)(op + (size_t)(n0 + tm + i) * Nn + c0 + tn + 4) = *(float4*)&acc[i][4];
  }
}

// ---------------------------------------------------------------------------
// K4: in-place softmax over axis=1 (n). Columns are the fast axis across
// lanes -> coalesced. Block = 64 cols x 4 n-stripes; online max/sum.
// ---------------------------------------------------------------------------
__global__ __launch_bounds__(256) void k_softmax(float* __restrict__ Sm)
{
  int b      = blockIdx.y;
  int col    = blockIdx.x * 64 + (threadIdx.x & 63);
  int stripe = threadIdx.x >> 6;
  float* p   = Sm + (size_t)b * Nn * Nn + col;
  int nstart = stripe * 256;
  float m = -1e30f, s = 0.f;
  for (int n = nstart; n < nstart + 256; ++n) {
    float v  = p[(size_t)n * Nn];
    float mn = fmaxf(m, v);
    s = s * __expf(m - mn) + __expf(v - mn);
    m = mn;
  }
  __shared__ float ms[4][64], ss[4][64];
  int c = threadIdx.x & 63;
  ms[stripe][c] = m;
  ss[stripe][c] = s;
  __syncthreads();
  float m0 = ms[0][c], m1 = ms[1][c], m2 = ms[2][c], m3 = ms[3][c];
  float M = fmaxf(fmaxf(m0, m1), fmaxf(m2, m3));
  float Ssum = ss[0][c] * __expf(m0 - M) + ss[1][c] * __expf(m1 - M) +
               ss[2][c] * __expf(m2 - M) + ss[3][c] * __expf(m3 - M);
  float inv = 1.f / Ssum;
  for (int n = nstart; n < nstart + 256; ++n) {
    float v = p[(size_t)n * Nn];
    p[(size_t)n * Nn] = __expf(v - M) * inv;
  }
}

// ---------------------------------------------------------------------------
// K5: Z[b,n,c] = sum_m (cheb_k[m,n]*S[b,m,n]) * x[b,m,c],  c in [0,768)
// A tile formed on the fly from cheb*S (both rows contiguous in n - no
// transpose). Same 128x128x8 fp32 tile as K3.
// ---------------------------------------------------------------------------
__global__ __launch_bounds__(256) void k_gemm_z(
    const float* __restrict__ chebk, const float* __restrict__ S,
    const float* __restrict__ x, float* __restrict__ Z)
{
  __shared__ float As[8][132];
  __shared__ float Bsh[8][132];
  int tid = threadIdx.x;
  int b   = blockIdx.z;
  int n0  = blockIdx.y * 128;
  int c0  = blockIdx.x * 128;
  const float* Sb = S + (size_t)b * Nn * Nn;
  const float* Xb = x + (size_t)b * Nn * CT;
  float acc[8][8] = {};
  int tm = (tid >> 4) * 8, tn = (tid & 15) * 8;
  int ak = tid >> 5, acol = (tid & 31) * 4;   // A: 8 rows(m) x 128 cols(n)
  int bk = tid >> 5, bc = (tid & 31) * 4;     // B: 8 rows(m) x 128 cols(c)

  for (int k0 = 0; k0 < Nn; k0 += 8) {
    float4 cv = *(const float4*)(chebk + (size_t)(k0 + ak) * Nn + n0 + acol);
    float4 sv = *(const float4*)(Sb + (size_t)(k0 + ak) * Nn + n0 + acol);
    float4 xv = *(const float4*)(Xb + (size_t)(k0 + bk) * CT + c0 + bc);
    __syncthreads();
    As[ak][acol + 0] = cv.x * sv.x;
    As[ak][acol + 1] = cv.y * sv.y;
    As[ak][acol + 2] = cv.z * sv.z;
    As[ak][acol + 3] = cv.w * sv.w;
    *(float4*)&Bsh[bk][bc] = xv;
    __syncthreads();
#pragma unroll
    for (int kk = 0; kk < 8; ++kk) {
      float a[8], bb[8];
      *(float4*)(a)      = *(const float4*)&As[kk][tm];
      *(float4*)(a + 4)  = *(const float4*)&As[kk][tm + 4];
      *(float4*)(bb)     = *(const float4*)&Bsh[kk][tn];
      *(float4*)(bb + 4) = *(const float4*)&Bsh[kk][tn + 4];
#pragma unroll
      for (int i = 0; i < 8; ++i)
#pragma unroll
        for (int j = 0; j < 8; ++j) acc[i][j] += a[i] * bb[j];
    }
  }
  float* op = Z + (size_t)b * Nn * CT;
#pragma unroll
  for (int i = 0; i < 8; ++i) {
    *(float4*)(op + (size_t)(n0 + tm + i) * CT + c0 + tn)     = *(float4*)&acc[i][0];
    *(float4*)(op + (size_t)(n0 + tm + i) * CT + c0 + tn + 4) = *(float4*)&acc[i][4];
  }
}

// ---------------------------------------------------------------------------
// K6: out[b,n,o,t] (+)= sum_f Z[b,n,f,t] * Theta_k[f,o];  relu at k==2.
// One block per (b,n): Z row (3 KB) + Theta_k (16 KB) staged in LDS.
// c = o*12 + t; thread handles c = tid, tid+256, tid+512 (coalesced writes).
// ---------------------------------------------------------------------------
__global__ __launch_bounds__(256) void k_theta(
    const float* __restrict__ Z, const float* __restrict__ Theta_k,
    float* __restrict__ out, int mode)
{
  __shared__ float Zs[CT];
  __shared__ float Th[Fn * On];
  int bn  = blockIdx.x;
  int tid = threadIdx.x;
  const float* zp = Z + (size_t)bn * CT;
  Zs[tid]       = zp[tid];
  Zs[tid + 256] = zp[tid + 256];
  Zs[tid + 512] = zp[tid + 512];
#pragma unroll
  for (int i = 0; i < 4; ++i)
    *(float4*)&Th[i * 1024 + tid * 4] =
        *(const float4*)(Theta_k + i * 1024 + tid * 4);
  __syncthreads();

  float o_acc[3] = {0.f, 0.f, 0.f};
  int cs[3] = {tid, tid + 256, tid + 512};
  int oo[3], tt[3];
#pragma unroll
  for (int q = 0; q < 3; ++q) { oo[q] = cs[q] / 12; tt[q] = cs[q] % 12; }
#pragma unroll 8
  for (int f = 0; f < Fn; ++f) {
#pragma unroll
    for (int q = 0; q < 3; ++q)
      o_acc[q] += Zs[f * 12 + tt[q]] * Th[f * 64 + oo[q]];
  }
  size_t base = (size_t)bn * CT;
  if (mode == 0) {
#pragma unroll
    for (int q = 0; q < 3; ++q) out[base + cs[q]] = o_acc[q];
  } else if (mode == 1) {
#pragma unroll
    for (int q = 0; q < 3; ++q) out[base + cs[q]] += o_acc[q];
  } else {
#pragma unroll
    for (int q = 0; q < 3; ++q)
      out[base + cs[q]] = fmaxf(out[base + cs[q]] + o_acc[q], 0.f);
  }
}

// ---------------------------------------------------------------------------
extern "C" void kernel_launch(void* const* d_in, const int* in_sizes, int n_in,
                              void* d_out, int out_size, void* d_ws,
                              size_t ws_size, hipStream_t stream)
{
  const float* x     = (const float*)d_in[0];
  const float* W1    = (const float*)d_in[1];
  const float* W2    = (const float*)d_in[2];
  const float* W3    = (const float*)d_in[3];
  const float* bs    = (const float*)d_in[4];
  const float* Vs    = (const float*)d_in[5];
  const float* cheb  = (const float*)d_in[6];
  const float* Theta = (const float*)d_in[7];
  float* out = (float*)d_out;
  float* ws  = (float*)d_ws;

  const size_t BNT = (size_t)Bn * Nn * Tn;     // 196,608
  const size_t BNN = (size_t)Bn * Nn * Nn;     // 16,777,216
  float* lhs = ws;
  float* rhs = lhs + BNT;
  float* P   = rhs + BNT;       // 64 MB
  float* Sm  = P + BNN;         // 64 MB
  float* Z   = P;               // alias: P dead after softmax

  // K1: lhs/rhs
  k_attn_lr<<<(Bn * Nn) / 4, 256, 0, stream>>>(x, W1, W2, W3, lhs, rhs);
  // K2: P = sigmoid(lhs . rhs^T + bs)
  k_prod_sig<<<(int)(BNN / 4 / 256), 256, 0, stream>>>(lhs, rhs, bs, P);
  // K3: Sm(pre) = Vs @ P[b]
  dim3 g3(Nn / 128, Nn / 128, Bn);
  k_gemm_vs<<<g3, 256, 0, stream>>>(Vs, P, Sm);
  // K4: softmax over axis=1, in place
  dim3 g4(Nn / 64, Bn);
  k_softmax<<<g4, 256, 0, stream>>>(Sm);
  // K5/K6 per Chebyshev order
  dim3 g5(CT / 128, Nn / 128, Bn);
  for (int k = 0; k < Kn; ++k) {
    k_gemm_z<<<g5, 256, 0, stream>>>(cheb + (size_t)k * Nn * Nn, Sm, x, Z);
    k_theta<<<Bn * Nn, 256, 0, stream>>>(Z, Theta + (size_t)k * Fn * On, out,
                                         k);
  }
}

// Round 2
// 741.642 us; speedup vs baseline: 2.4824x; 2.4824x over previous
//
#include <hip/hip_runtime.h>

// MAMGCN submodule: B=16, N=1024, F_IN=64, T=12, K=3, F_OUT=64
// R1: bf16-MFMA rewrite of the two big contractions (was fp32 VALU at 82 TF).
//   K3: Spre[b,c,n'] (transposed store) = Vs16[n',m] @ Pt[b,c,m]^T   (MFMA)
//   K4: softmax over contiguous n' axis, fp32 -> St bf16 [b,c,n']
//   K5: Z[b,n,c'] = AS[b,n,m] @ xT[b,c',m]^T                         (MFMA)
// AS = cheb^T (.) S built per-k by elementwise kernel; x transposed once.

typedef __attribute__((ext_vector_type(8))) short v8s;   // bf16x8 (4 VGPR)
typedef __attribute__((ext_vector_type(4))) float v4f;   // fp32x4 acc
typedef unsigned short u16;
typedef unsigned int u32;

#define Bn 16
#define Nn 1024
#define Tn 12
#define CT 768

__device__ inline u16 f2bf(float f) {          // round-half-up bf16
  u32 u = __float_as_uint(f);
  return (u16)((u + 0x8000u) >> 16);
}
__device__ inline float bf2f(u16 h) { return __uint_as_float(((u32)h) << 16); }

__device__ inline void gl_lds16(const void* g, void* l) {
  __builtin_amdgcn_global_load_lds(
      (const __attribute__((address_space(1))) u32*)g,
      (__attribute__((address_space(3))) u32*)l, 16, 0, 0);
}

// ---------------------------------------------------------------------------
// K1: lhs[b,n,t'] = (sum_t x*W1) @ W2 ; rhs[b,n,t] = sum_f W3*x  (unchanged)
// ---------------------------------------------------------------------------
__global__ __launch_bounds__(256) void k_attn_lr(
    const float* __restrict__ x, const float* __restrict__ W1,
    const float* __restrict__ W2, const float* __restrict__ W3,
    float* __restrict__ lhs, float* __restrict__ rhs)
{
  int bn   = blockIdx.x * 4 + (threadIdx.x >> 6);
  int lane = threadIdx.x & 63;                     // = f
  const float* xp = x + (size_t)bn * (64 * Tn) + lane * Tn;
  float4 v0 = *(const float4*)(xp);
  float4 v1 = *(const float4*)(xp + 4);
  float4 v2 = *(const float4*)(xp + 8);
  float xv[12] = {v0.x, v0.y, v0.z, v0.w, v1.x, v1.y, v1.z, v1.w,
                  v2.x, v2.y, v2.z, v2.w};
  float w3 = W3[lane];
  float tmp = 0.f;
#pragma unroll
  for (int t = 0; t < 12; ++t) tmp += xv[t] * W1[t];
#pragma unroll
  for (int t = 0; t < 12; ++t) {
    float v = tmp * W2[lane * 12 + t];
    float r = w3 * xv[t];
#pragma unroll
    for (int off = 32; off; off >>= 1) {
      v += __shfl_xor(v, off);
      r += __shfl_xor(r, off);
    }
    if (lane == t) {
      lhs[(size_t)bn * 12 + t] = v;
      rhs[(size_t)bn * 12 + t] = r;
    }
  }
}

// ---------------------------------------------------------------------------
// Pack kernels: Vs -> bf16 ; x[b,m,c] -> xT[b,c,m] bf16 (LDS tile transpose)
// ---------------------------------------------------------------------------
__global__ __launch_bounds__(256) void k_vs16(const float* __restrict__ Vs,
                                              u16* __restrict__ V16)
{
  size_t i = (size_t)blockIdx.x * 256 + threadIdx.x;
  float4 v = *(const float4*)(Vs + i * 4);
  *(ushort4*)(V16 + i * 4) =
      make_ushort4(f2bf(v.x), f2bf(v.y), f2bf(v.z), f2bf(v.w));
}

__global__ __launch_bounds__(256) void k_xT(const float* __restrict__ x,
                                            u16* __restrict__ xT)
{
  __shared__ float t[64][65];
  int b = blockIdx.z, m0 = blockIdx.y * 64, c0 = blockIdx.x * 64;
  const float* xb = x + (size_t)b * Nn * CT;
  int tid = threadIdx.x;
#pragma unroll
  for (int q = 0; q < 16; ++q) {
    int idx = q * 256 + tid;
    int i = idx >> 6, j = idx & 63;   // i: m-local, j: c-local
    t[i][j] = xb[(size_t)(m0 + i) * CT + c0 + j];
  }
  __syncthreads();
  u16* xtb = xT + (size_t)b * CT * Nn;
#pragma unroll
  for (int q = 0; q < 16; ++q) {
    int idx = q * 256 + tid;
    int i = idx >> 6, j = idx & 63;   // i: c-local, j: m-local
    xtb[(size_t)(c0 + i) * Nn + m0 + j] = f2bf(t[j][i]);
  }
}

// ---------------------------------------------------------------------------
// K2: Pt[b,c,m] = bf16(sigmoid(lhs[b,m,:].rhs[b,c,:] + bs[m,c]))
// Full lhs[b] panel staged in LDS (padded stride 13 -> conflict-free).
// ---------------------------------------------------------------------------
__global__ __launch_bounds__(256) void k_prod(
    const float* __restrict__ lhs, const float* __restrict__ rhs,
    const float* __restrict__ bs, u16* __restrict__ Pt)
{
  __shared__ float ls[1024][13];
  __shared__ float rs[16][12];
  int b = blockIdx.y, c0 = blockIdx.x * 16;
  int tid = threadIdx.x;
  const float* lb = lhs + (size_t)b * Nn * 12;
#pragma unroll
  for (int mq = 0; mq < 4; ++mq) {
    int m = mq * 256 + tid;
    const float* p = lb + (size_t)m * 12;
    float4 a0 = *(const float4*)p;
    float4 a1 = *(const float4*)(p + 4);
    float4 a2 = *(const float4*)(p + 8);
    ls[m][0] = a0.x; ls[m][1] = a0.y; ls[m][2]  = a0.z; ls[m][3]  = a0.w;
    ls[m][4] = a1.x; ls[m][5] = a1.y; ls[m][6]  = a1.z; ls[m][7]  = a1.w;
    ls[m][8] = a2.x; ls[m][9] = a2.y; ls[m][10] = a2.z; ls[m][11] = a2.w;
  }
  if (tid < 192) {
    int cc = tid / 12, tt = tid % 12;
    rs[cc][tt] = rhs[((size_t)b * Nn + c0 + cc) * 12 + tt];
  }
  __syncthreads();
  u16* Pb = Pt + ((size_t)b << 20);
#pragma unroll
  for (int mq = 0; mq < 4; ++mq) {
    int m = mq * 256 + tid;
    float l[12];
#pragma unroll
    for (int t = 0; t < 12; ++t) l[t] = ls[m][t];
#pragma unroll
    for (int cc = 0; cc < 16; ++cc) {
      float d = bs[(size_t)m * Nn + c0 + cc];
#pragma unroll
      for (int t = 0; t < 12; ++t) d += l[t] * rs[cc][t];
      float sg = 1.f / (1.f + __expf(-d));
      Pb[(size_t)(c0 + cc) * Nn + m] = f2bf(sg);
    }
  }
}

// ---------------------------------------------------------------------------
// MFMA GEMM (m97 structure): 128x128 tile, BK=64, 4 waves (2x2), 16x16x32.
// A rows: M-dim, K-contiguous bf16. B rows: N-dim, K-contiguous bf16.
// LDS XOR-swizzled (chunk ^= row&7) via pre-swizzled global_load_lds source.
// K3 variant: transposed fp32 store (D rows are 4-consecutive -> float4).
// ---------------------------------------------------------------------------
__global__ __launch_bounds__(256) void k_gemm_vsP(
    const u16* __restrict__ A,    // Vs16 [1024][1024]
    const u16* __restrict__ Pt,   // [16][1024][1024]  (c, m)
    float* __restrict__ Spre)     // [16][1024][1024]  (c, n')
{
  __shared__ u16 As[8192];
  __shared__ u16 Bs[8192];
  const int tid = threadIdx.x;
  const int lane = tid & 63;
  const int w = tid >> 6, wr = w >> 1, wc = w & 1;
  const int b = blockIdx.z;
  const int n0 = blockIdx.y * 128;   // M (n')
  const int c0 = blockIdx.x * 128;   // N (c)
  const u16* Bg = Pt + ((size_t)b << 20);

  size_t aoff[4], boff[4];
  u16 *alds[4], *blds[4];
#pragma unroll
  for (int i = 0; i < 4; ++i) {
    int ch = (w * 4 + i) * 64 + lane;
    int row = ch >> 3;
    int kc = (ch & 7) ^ (row & 7);            // pre-swizzled source chunk
    aoff[i] = (size_t)(n0 + row) * Nn + kc * 8;
    boff[i] = (size_t)(c0 + row) * Nn + kc * 8;
    alds[i] = (u16*)As + (size_t)(w * 4 + i) * 512;
    blds[i] = (u16*)Bs + (size_t)(w * 4 + i) * 512;
  }

  v4f acc[4][4] = {};
  const int l15 = lane & 15, h = lane >> 4;

  for (int k0 = 0; k0 < Nn; k0 += 64) {
    __syncthreads();
#pragma unroll
    for (int i = 0; i < 4; ++i) {
      gl_lds16(A + aoff[i] + k0, alds[i]);
      gl_lds16(Bg + boff[i] + k0, blds[i]);
    }
    __syncthreads();
#pragma unroll
    for (int kk = 0; kk < 2; ++kk) {
      v8s a[4], bf[4];
#pragma unroll
      for (int mi = 0; mi < 4; ++mi) {
        int rA = wr * 64 + mi * 16 + l15;
        a[mi] = *(const v8s*)((const u16*)As + rA * 64 +
                              (((kk * 4 + h) ^ (rA & 7)) * 8));
      }
#pragma unroll
      for (int nj = 0; nj < 4; ++nj) {
        int rB = wc * 64 + nj * 16 + l15;
        bf[nj] = *(const v8s*)((const u16*)Bs + rB * 64 +
                               (((kk * 4 + h) ^ (rB & 7)) * 8));
      }
#pragma unroll
      for (int mi = 0; mi < 4; ++mi)
#pragma unroll
        for (int nj = 0; nj < 4; ++nj)
          acc[mi][nj] = __builtin_amdgcn_mfma_f32_16x16x32_bf16(
              a[mi], bf[nj], acc[mi][nj], 0, 0, 0);
    }
  }
  // transposed store: Spre[b][c][n'], 4 consecutive n' per lane -> float4
  float* Sp = Spre + ((size_t)b << 20);
#pragma unroll
  for (int mi = 0; mi < 4; ++mi) {
    int rown = n0 + wr * 64 + mi * 16 + h * 4;
#pragma unroll
    for (int nj = 0; nj < 4; ++nj) {
      int colc = c0 + wc * 64 + nj * 16 + l15;
      *(float4*)(Sp + (size_t)colc * Nn + rown) = *(float4*)&acc[mi][nj];
    }
  }
}

__global__ __launch_bounds__(256) void k_gemm_z(
    const u16* __restrict__ AS,   // [16][1024][1024]  (n, m)
    const u16* __restrict__ xT,   // [16][768][1024]   (c', m)
    float* __restrict__ Z)        // [16][1024][768]   (n, c')
{
  __shared__ u16 As[8192];
  __shared__ u16 Bs[8192];
  const int tid = threadIdx.x;
  const int lane = tid & 63;
  const int w = tid >> 6, wr = w >> 1, wc = w & 1;
  const int b = blockIdx.z;
  const int n0 = blockIdx.y * 128;   // M (n)
  const int c0 = blockIdx.x * 128;   // N (c'), 6 blocks
  const u16* Ag = AS + ((size_t)b << 20);
  const u16* Bg = xT + (size_t)b * CT * Nn;

  size_t aoff[4], boff[4];
  u16 *alds[4], *blds[4];
#pragma unroll
  for (int i = 0; i < 4; ++i) {
    int ch = (w * 4 + i) * 64 + lane;
    int row = ch >> 3;
    int kc = (ch & 7) ^ (row & 7);
    aoff[i] = (size_t)(n0 + row) * Nn + kc * 8;
    boff[i] = (size_t)(c0 + row) * Nn + kc * 8;
    alds[i] = (u16*)As + (size_t)(w * 4 + i) * 512;
    blds[i] = (u16*)Bs + (size_t)(w * 4 + i) * 512;
  }

  v4f acc[4][4] = {};
  const int l15 = lane & 15, h = lane >> 4;

  for (int k0 = 0; k0 < Nn; k0 += 64) {
    __syncthreads();
#pragma unroll
    for (int i = 0; i < 4; ++i) {
      gl_lds16(Ag + aoff[i] + k0, alds[i]);
      gl_lds16(Bg + boff[i] + k0, blds[i]);
    }
    __syncthreads();
#pragma unroll
    for (int kk = 0; kk < 2; ++kk) {
      v8s a[4], bf[4];
#pragma unroll
      for (int mi = 0; mi < 4; ++mi) {
        int rA = wr * 64 + mi * 16 + l15;
        a[mi] = *(const v8s*)((const u16*)As + rA * 64 +
                              (((kk * 4 + h) ^ (rA & 7)) * 8));
      }
#pragma unroll
      for (int nj = 0; nj < 4; ++nj) {
        int rB = wc * 64 + nj * 16 + l15;
        bf[nj] = *(const v8s*)((const u16*)Bs + rB * 64 +
                               (((kk * 4 + h) ^ (rB & 7)) * 8));
      }
#pragma unroll
      for (int mi = 0; mi < 4; ++mi)
#pragma unroll
        for (int nj = 0; nj < 4; ++nj)
          acc[mi][nj] = __builtin_amdgcn_mfma_f32_16x16x32_bf16(
              a[mi], bf[nj], acc[mi][nj], 0, 0, 0);
    }
  }
  float* Zb = Z + (size_t)b * Nn * CT;
#pragma unroll
  for (int mi = 0; mi < 4; ++mi) {
    int rown = n0 + wr * 64 + mi * 16 + h * 4;
#pragma unroll
    for (int nj = 0; nj < 4; ++nj) {
      int colc = c0 + wc * 64 + nj * 16 + l15;
#pragma unroll
      for (int r = 0; r < 4; ++r)
        Zb[(size_t)(rown + r) * CT + colc] = acc[mi][nj][r];
    }
  }
}

// ---------------------------------------------------------------------------
// K4: softmax over contiguous n' axis of Spre[b,c,:] -> St bf16. Wave/row.
// ---------------------------------------------------------------------------
__global__ __launch_bounds__(256) void k_soft(const float* __restrict__ Spre,
                                              u16* __restrict__ St)
{
  int wid = threadIdx.x >> 6, lane = threadIdx.x & 63;
  int row = blockIdx.x * 4 + wid;   // c
  int b = blockIdx.y;
  const float* p = Spre + ((size_t)b << 20) + (size_t)row * Nn;
  float v[16];
#pragma unroll
  for (int q = 0; q < 4; ++q) {
    float4 t = *(const float4*)(p + q * 256 + lane * 4);
    v[q * 4 + 0] = t.x; v[q * 4 + 1] = t.y;
    v[q * 4 + 2] = t.z; v[q * 4 + 3] = t.w;
  }
  float M = v[0];
#pragma unroll
  for (int i = 1; i < 16; ++i) M = fmaxf(M, v[i]);
#pragma unroll
  for (int off = 32; off; off >>= 1) M = fmaxf(M, __shfl_xor(M, off));
  float s = 0.f;
#pragma unroll
  for (int i = 0; i < 16; ++i) { v[i] = __expf(v[i] - M); s += v[i]; }
#pragma unroll
  for (int off = 32; off; off >>= 1) s += __shfl_xor(s, off);
  float inv = 1.f / s;
  u16* o = St + ((size_t)b << 20) + (size_t)row * Nn;
#pragma unroll
  for (int q = 0; q < 4; ++q) {
    u32 w0 = (u32)f2bf(v[q * 4 + 0] * inv) | ((u32)f2bf(v[q * 4 + 1] * inv) << 16);
    u32 w1 = (u32)f2bf(v[q * 4 + 2] * inv) | ((u32)f2bf(v[q * 4 + 3] * inv) << 16);
    *(uint2*)(o + q * 256 + lane * 4) = make_uint2(w0, w1);
  }
}

// ---------------------------------------------------------------------------
// AS[b,n,m] = bf16( cheb_k[m,n] * S[b,m,n] )   (St stored [b][n][m])
// cheb tile transposed through LDS; St/AS accesses coalesced.
// ---------------------------------------------------------------------------
__global__ __launch_bounds__(256) void k_as(const float* __restrict__ chebk,
                                            const u16* __restrict__ St,
                                            u16* __restrict__ AS)
{
  __shared__ float ch[64][65];
  int b = blockIdx.z, m0 = blockIdx.y * 64, n0 = blockIdx.x * 64;
  int tid = threadIdx.x;
#pragma unroll
  for (int q = 0; q < 16; ++q) {
    int idx = q * 256 + tid;
    int i = idx >> 6, j = idx & 63;   // i: m-local, j: n-local
    ch[i][j] = chebk[(size_t)(m0 + i) * Nn + n0 + j];
  }
  __syncthreads();
  const u16* Stb = St + ((size_t)b << 20);
  u16* ASb = AS + ((size_t)b << 20);
#pragma unroll
  for (int q = 0; q < 16; ++q) {
    int idx = q * 256 + tid;
    int i = idx >> 6, j = idx & 63;   // i: n-local, j: m-local
    size_t off = (size_t)(n0 + i) * Nn + m0 + j;
    ASb[off] = f2bf(ch[j][i] * bf2f(Stb[off]));
  }
}

// ---------------------------------------------------------------------------
// K6: out[b,n,o,t] (+)= sum_f Z[b,n,f,t]*Theta_k[f,o]; relu at k==2.
// ---------------------------------------------------------------------------
__global__ __launch_bounds__(256) void k_theta(
    const float* __restrict__ Z, const float* __restrict__ Theta_k,
    float* __restrict__ out, int mode)
{
  __shared__ float Zs[CT];
  __shared__ float Th[64 * 64];
  int bn  = blockIdx.x;
  int tid = threadIdx.x;
  const float* zp = Z + (size_t)bn * CT;
  Zs[tid]       = zp[tid];
  Zs[tid + 256] = zp[tid + 256];
  Zs[tid + 512] = zp[tid + 512];
#pragma unroll
  for (int i = 0; i < 4; ++i)
    *(float4*)&Th[i * 1024 + tid * 4] =
        *(const float4*)(Theta_k + i * 1024 + tid * 4);
  __syncthreads();

  float o_acc[3] = {0.f, 0.f, 0.f};
  int cs[3] = {tid, tid + 256, tid + 512};
  int oo[3], tt[3];
#pragma unroll
  for (int q = 0; q < 3; ++q) { oo[q] = cs[q] / 12; tt[q] = cs[q] % 12; }
#pragma unroll 8
  for (int f = 0; f < 64; ++f) {
#pragma unroll
    for (int q = 0; q < 3; ++q)
      o_acc[q] += Zs[f * 12 + tt[q]] * Th[f * 64 + oo[q]];
  }
  size_t base = (size_t)bn * CT;
  if (mode == 0) {
#pragma unroll
    for (int q = 0; q < 3; ++q) out[base + cs[q]] = o_acc[q];
  } else if (mode == 1) {
#pragma unroll
    for (int q = 0; q < 3; ++q) out[base + cs[q]] += o_acc[q];
  } else {
#pragma unroll
    for (int q = 0; q < 3; ++q)
      out[base + cs[q]] = fmaxf(out[base + cs[q]] + o_acc[q], 0.f);
  }
}

// ---------------------------------------------------------------------------
extern "C" void kernel_launch(void* const* d_in, const int* in_sizes, int n_in,
                              void* d_out, int out_size, void* d_ws,
                              size_t ws_size, hipStream_t stream)
{
  const float* x     = (const float*)d_in[0];
  const float* W1    = (const float*)d_in[1];
  const float* W2    = (const float*)d_in[2];
  const float* W3    = (const float*)d_in[3];
  const float* bs    = (const float*)d_in[4];
  const float* Vs    = (const float*)d_in[5];
  const float* cheb  = (const float*)d_in[6];
  const float* Theta = (const float*)d_in[7];
  float* out = (float*)d_out;

  // ws layout (155.5 MB): lhs|rhs | Pt/AS 32MB | Spre/Z 64MB | St 32MB |
  //                       xT 24MB | Vs16 2MB
  const size_t BNT = (size_t)Bn * Nn * Tn;
  float* lhs  = (float*)d_ws;
  float* rhs  = lhs + BNT;
  u16*   Pt   = (u16*)(rhs + BNT);
  u16*   AS   = Pt;                                  // alias (Pt dead post-K3)
  float* Spre = (float*)(Pt + ((size_t)16 << 20));
  float* Z    = Spre;                                // alias (Spre dead post-K4)
  u16*   St   = (u16*)(Spre + ((size_t)16 << 20));
  u16*   xT   = St + ((size_t)16 << 20);
  u16*   Vs16 = xT + (size_t)Bn * CT * Nn;

  k_attn_lr<<<(Bn * Nn) / 4, 256, 0, stream>>>(x, W1, W2, W3, lhs, rhs);
  k_vs16<<<1024, 256, 0, stream>>>(Vs, Vs16);
  k_xT<<<dim3(CT / 64, Nn / 64, Bn), 256, 0, stream>>>(x, xT);
  k_prod<<<dim3(Nn / 16, Bn), 256, 0, stream>>>(lhs, rhs, bs, Pt);
  k_gemm_vsP<<<dim3(Nn / 128, Nn / 128, Bn), 256, 0, stream>>>(Vs16, Pt, Spre);
  k_soft<<<dim3(Nn / 4, Bn), 256, 0, stream>>>(Spre, St);
  for (int k = 0; k < 3; ++k) {
    k_as<<<dim3(Nn / 64, Nn / 64, Bn), 256, 0, stream>>>(
        cheb + ((size_t)k << 20), St, AS);
    k_gemm_z<<<dim3(CT / 128, Nn / 128, Bn), 256, 0, stream>>>(AS, xT, Z);
    k_theta<<<Bn * Nn, 256, 0, stream>>>(Z, Theta + (size_t)k * 4096, out, k);
  }
}

// Round 3
// 578.496 us; speedup vs baseline: 3.1824x; 1.2820x over previous
//
#include <hip/hip_runtime.h>

// MAMGCN submodule: B=16, N=1024, F_IN=64, T=12, K=3, F_OUT=64
// R3: eliminate k_theta by commuting Theta through the m-contraction:
//   out[b,n,(o,t)] = relu( sum_k sum_m AS_k[b,n,m] * TXk[b,(o,t),m] )
//   TXk[b,(o,t),m] = sum_f x[b,m,(f,t)] * Theta_k[f,o]   (tiny MFMA kernel)
// k_gemm_out writes straight into out (relu fused at k==2). k_xT/k_theta gone.

typedef __attribute__((ext_vector_type(8))) short v8s;   // bf16x8 (4 VGPR)
typedef __attribute__((ext_vector_type(4))) float v4f;   // fp32x4 acc
typedef unsigned short u16;
typedef unsigned int u32;

#define Bn 16
#define Nn 1024
#define Tn 12
#define CT 768

__device__ inline u16 f2bf(float f) {
  u32 u = __float_as_uint(f);
  return (u16)((u + 0x8000u) >> 16);
}
__device__ inline float bf2f(u16 h) { return __uint_as_float(((u32)h) << 16); }

__device__ inline void gl_lds16(const void* g, void* l) {
  __builtin_amdgcn_global_load_lds(
      (const __attribute__((address_space(1))) u32*)g,
      (__attribute__((address_space(3))) u32*)l, 16, 0, 0);
}

// ---------------------------------------------------------------------------
// K1: lhs[b,n,t'] = (sum_t x*W1) @ W2 ; rhs[b,n,t] = sum_f W3*x
// ---------------------------------------------------------------------------
__global__ __launch_bounds__(256) void k_attn_lr(
    const float* __restrict__ x, const float* __restrict__ W1,
    const float* __restrict__ W2, const float* __restrict__ W3,
    float* __restrict__ lhs, float* __restrict__ rhs)
{
  int bn   = blockIdx.x * 4 + (threadIdx.x >> 6);
  int lane = threadIdx.x & 63;                     // = f
  const float* xp = x + (size_t)bn * (64 * Tn) + lane * Tn;
  float4 v0 = *(const float4*)(xp);
  float4 v1 = *(const float4*)(xp + 4);
  float4 v2 = *(const float4*)(xp + 8);
  float xv[12] = {v0.x, v0.y, v0.z, v0.w, v1.x, v1.y, v1.z, v1.w,
                  v2.x, v2.y, v2.z, v2.w};
  float w3 = W3[lane];
  float tmp = 0.f;
#pragma unroll
  for (int t = 0; t < 12; ++t) tmp += xv[t] * W1[t];
#pragma unroll
  for (int t = 0; t < 12; ++t) {
    float v = tmp * W2[lane * 12 + t];
    float r = w3 * xv[t];
#pragma unroll
    for (int off = 32; off; off >>= 1) {
      v += __shfl_xor(v, off);
      r += __shfl_xor(r, off);
    }
    if (lane == t) {
      lhs[(size_t)bn * 12 + t] = v;
      rhs[(size_t)bn * 12 + t] = r;
    }
  }
}

// ---------------------------------------------------------------------------
// Vs -> bf16
// ---------------------------------------------------------------------------
__global__ __launch_bounds__(256) void k_vs16(const float* __restrict__ Vs,
                                              u16* __restrict__ V16)
{
  size_t i = (size_t)blockIdx.x * 256 + threadIdx.x;
  float4 v = *(const float4*)(Vs + i * 4);
  *(ushort4*)(V16 + i * 4) =
      make_ushort4(f2bf(v.x), f2bf(v.y), f2bf(v.z), f2bf(v.w));
}

// ---------------------------------------------------------------------------
// x[b,m,(f,t)] -> xTf[b][t][m][f] bf16 (t-major, f-contiguous)
// ---------------------------------------------------------------------------
__global__ __launch_bounds__(256) void k_xtf(const float* __restrict__ x,
                                             u16* __restrict__ xTf)
{
  __shared__ u16 xs[32][768];
  int b = blockIdx.y, m0 = blockIdx.x * 32;
  const float* xb = x + ((size_t)b * Nn + m0) * CT;
  int tid = threadIdx.x;
#pragma unroll
  for (int q = 0; q < 24; ++q) {
    int idx = (q * 256 + tid) * 4;     // flat fp32 in 32x768
    int i = idx / 768, j = idx % 768;  // j..j+3 within row (768%4==0)
    float4 v = *(const float4*)(xb + (size_t)i * CT + j);
    xs[i][j]     = f2bf(v.x);
    xs[i][j + 1] = f2bf(v.y);
    xs[i][j + 2] = f2bf(v.z);
    xs[i][j + 3] = f2bf(v.w);
  }
  __syncthreads();
#pragma unroll
  for (int q = 0; q < 24; ++q) {
    int flat = q * 256 + tid;          // (t*32 + i)*16 + fq
    int t = flat >> 9;
    int rem = flat & 511;
    int i = rem >> 4, fq = rem & 15;
    ushort4 o;
    o.x = xs[i][(fq * 4 + 0) * 12 + t];
    o.y = xs[i][(fq * 4 + 1) * 12 + t];
    o.z = xs[i][(fq * 4 + 2) * 12 + t];
    o.w = xs[i][(fq * 4 + 3) * 12 + t];
    *(ushort4*)(xTf + (((size_t)b * 12 + t) * Nn + m0 + i) * 64 + fq * 4) = o;
  }
}

// ---------------------------------------------------------------------------
// K2: Pt[b,c,m] = bf16(sigmoid(lhs[b,m,:].rhs[b,c,:] + bs[m,c]))
// ---------------------------------------------------------------------------
__global__ __launch_bounds__(256) void k_prod(
    const float* __restrict__ lhs, const float* __restrict__ rhs,
    const float* __restrict__ bs, u16* __restrict__ Pt)
{
  __shared__ float ls[1024][13];
  __shared__ float rs[16][12];
  int b = blockIdx.y, c0 = blockIdx.x * 16;
  int tid = threadIdx.x;
  const float* lb = lhs + (size_t)b * Nn * 12;
#pragma unroll
  for (int mq = 0; mq < 4; ++mq) {
    int m = mq * 256 + tid;
    const float* p = lb + (size_t)m * 12;
    float4 a0 = *(const float4*)p;
    float4 a1 = *(const float4*)(p + 4);
    float4 a2 = *(const float4*)(p + 8);
    ls[m][0] = a0.x; ls[m][1] = a0.y; ls[m][2]  = a0.z; ls[m][3]  = a0.w;
    ls[m][4] = a1.x; ls[m][5] = a1.y; ls[m][6]  = a1.z; ls[m][7]  = a1.w;
    ls[m][8] = a2.x; ls[m][9] = a2.y; ls[m][10] = a2.z; ls[m][11] = a2.w;
  }
  if (tid < 192) {
    int cc = tid / 12, tt = tid % 12;
    rs[cc][tt] = rhs[((size_t)b * Nn + c0 + cc) * 12 + tt];
  }
  __syncthreads();
  u16* Pb = Pt + ((size_t)b << 20);
#pragma unroll
  for (int mq = 0; mq < 4; ++mq) {
    int m = mq * 256 + tid;
    float l[12];
#pragma unroll
    for (int t = 0; t < 12; ++t) l[t] = ls[m][t];
#pragma unroll
    for (int cc = 0; cc < 16; ++cc) {
      float d = bs[(size_t)m * Nn + c0 + cc];
#pragma unroll
      for (int t = 0; t < 12; ++t) d += l[t] * rs[cc][t];
      float sg = 1.f / (1.f + __expf(-d));
      Pb[(size_t)(c0 + cc) * Nn + m] = f2bf(sg);
    }
  }
}

// ---------------------------------------------------------------------------
// K3: Spre[b,c,n'] (transposed store) = Vs16[n',m] @ Pt[b,c,m]^T  (MFMA)
// ---------------------------------------------------------------------------
__global__ __launch_bounds__(256) void k_gemm_vsP(
    const u16* __restrict__ A, const u16* __restrict__ Pt,
    float* __restrict__ Spre)
{
  __shared__ u16 As[8192];
  __shared__ u16 Bs[8192];
  const int tid = threadIdx.x;
  const int lane = tid & 63;
  const int w = tid >> 6, wr = w >> 1, wc = w & 1;
  const int b = blockIdx.z;
  const int n0 = blockIdx.y * 128;
  const int c0 = blockIdx.x * 128;
  const u16* Bg = Pt + ((size_t)b << 20);

  size_t aoff[4], boff[4];
  u16 *alds[4], *blds[4];
#pragma unroll
  for (int i = 0; i < 4; ++i) {
    int ch = (w * 4 + i) * 64 + lane;
    int row = ch >> 3;
    int kc = (ch & 7) ^ (row & 7);
    aoff[i] = (size_t)(n0 + row) * Nn + kc * 8;
    boff[i] = (size_t)(c0 + row) * Nn + kc * 8;
    alds[i] = (u16*)As + (size_t)(w * 4 + i) * 512;
    blds[i] = (u16*)Bs + (size_t)(w * 4 + i) * 512;
  }

  v4f acc[4][4] = {};
  const int l15 = lane & 15, h = lane >> 4;

  for (int k0 = 0; k0 < Nn; k0 += 64) {
    __syncthreads();
#pragma unroll
    for (int i = 0; i < 4; ++i) {
      gl_lds16(A + aoff[i] + k0, alds[i]);
      gl_lds16(Bg + boff[i] + k0, blds[i]);
    }
    __syncthreads();
#pragma unroll
    for (int kk = 0; kk < 2; ++kk) {
      v8s a[4], bf[4];
#pragma unroll
      for (int mi = 0; mi < 4; ++mi) {
        int rA = wr * 64 + mi * 16 + l15;
        a[mi] = *(const v8s*)((const u16*)As + rA * 64 +
                              (((kk * 4 + h) ^ (rA & 7)) * 8));
      }
#pragma unroll
      for (int nj = 0; nj < 4; ++nj) {
        int rB = wc * 64 + nj * 16 + l15;
        bf[nj] = *(const v8s*)((const u16*)Bs + rB * 64 +
                               (((kk * 4 + h) ^ (rB & 7)) * 8));
      }
#pragma unroll
      for (int mi = 0; mi < 4; ++mi)
#pragma unroll
        for (int nj = 0; nj < 4; ++nj)
          acc[mi][nj] = __builtin_amdgcn_mfma_f32_16x16x32_bf16(
              a[mi], bf[nj], acc[mi][nj], 0, 0, 0);
    }
  }
  float* Sp = Spre + ((size_t)b << 20);
#pragma unroll
  for (int mi = 0; mi < 4; ++mi) {
    int rown = n0 + wr * 64 + mi * 16 + h * 4;
#pragma unroll
    for (int nj = 0; nj < 4; ++nj) {
      int colc = c0 + wc * 64 + nj * 16 + l15;
      *(float4*)(Sp + (size_t)colc * Nn + rown) = *(float4*)&acc[mi][nj];
    }
  }
}

// ---------------------------------------------------------------------------
// K4: softmax over contiguous n' axis of Spre[b,c,:] -> St bf16. Wave/row.
// ---------------------------------------------------------------------------
__global__ __launch_bounds__(256) void k_soft(const float* __restrict__ Spre,
                                              u16* __restrict__ St)
{
  int wid = threadIdx.x >> 6, lane = threadIdx.x & 63;
  int row = blockIdx.x * 4 + wid;
  int b = blockIdx.y;
  const float* p = Spre + ((size_t)b << 20) + (size_t)row * Nn;
  float v[16];
#pragma unroll
  for (int q = 0; q < 4; ++q) {
    float4 t = *(const float4*)(p + q * 256 + lane * 4);
    v[q * 4 + 0] = t.x; v[q * 4 + 1] = t.y;
    v[q * 4 + 2] = t.z; v[q * 4 + 3] = t.w;
  }
  float M = v[0];
#pragma unroll
  for (int i = 1; i < 16; ++i) M = fmaxf(M, v[i]);
#pragma unroll
  for (int off = 32; off; off >>= 1) M = fmaxf(M, __shfl_xor(M, off));
  float s = 0.f;
#pragma unroll
  for (int i = 0; i < 16; ++i) { v[i] = __expf(v[i] - M); s += v[i]; }
#pragma unroll
  for (int off = 32; off; off >>= 1) s += __shfl_xor(s, off);
  float inv = 1.f / s;
  u16* o = St + ((size_t)b << 20) + (size_t)row * Nn;
#pragma unroll
  for (int q = 0; q < 4; ++q) {
    u32 w0 = (u32)f2bf(v[q * 4 + 0] * inv) | ((u32)f2bf(v[q * 4 + 1] * inv) << 16);
    u32 w1 = (u32)f2bf(v[q * 4 + 2] * inv) | ((u32)f2bf(v[q * 4 + 3] * inv) << 16);
    *(uint2*)(o + q * 256 + lane * 4) = make_uint2(w0, w1);
  }
}

// ---------------------------------------------------------------------------
// ThT[k*64+o][f] = bf16(Theta[k][f][o])  (tiny one-block transpose)
// ---------------------------------------------------------------------------
__global__ __launch_bounds__(256) void k_tht(const float* __restrict__ Theta,
                                             u16* __restrict__ ThT)
{
  int tid = threadIdx.x;
#pragma unroll
  for (int q = 0; q < 48; ++q) {
    int flat = q * 256 + tid;          // ko*64 + f
    int ko = flat >> 6, f = flat & 63;
    int k = ko >> 6, o = ko & 63;
    ThT[flat] = f2bf(Theta[((size_t)k * 64 + f) * 64 + o]);
  }
}

// ---------------------------------------------------------------------------
// AS_k[b,n,m] = bf16(cheb_k[m,n] * S[b,m,n]) for all 3 k in one pass.
// ---------------------------------------------------------------------------
__global__ __launch_bounds__(256) void k_as3(const float* __restrict__ cheb,
                                             const u16* __restrict__ St,
                                             u16* __restrict__ AS)
{
  __shared__ float ch[3][64][65];
  int b = blockIdx.z, m0 = blockIdx.y * 64, n0 = blockIdx.x * 64;
  int tid = threadIdx.x;
#pragma unroll
  for (int kk = 0; kk < 3; ++kk)
#pragma unroll
    for (int q = 0; q < 16; ++q) {
      int idx = q * 256 + tid;
      int i = idx >> 6, j = idx & 63;   // i: m-local, j: n-local
      ch[kk][i][j] =
          cheb[((size_t)kk << 20) + (size_t)(m0 + i) * Nn + n0 + j];
    }
  __syncthreads();
  const u16* Stb = St + ((size_t)b << 20);
#pragma unroll
  for (int q = 0; q < 16; ++q) {
    int idx = q * 256 + tid;
    int i = idx >> 6, j = idx & 63;     // i: n-local, j: m-local
    size_t off = (size_t)(n0 + i) * Nn + m0 + j;
    float s = bf2f(Stb[off]);
#pragma unroll
    for (int kk = 0; kk < 3; ++kk)
      AS[((size_t)(kk * 16 + b) << 20) + off] = f2bf(ch[kk][j][i] * s);
  }
}

// ---------------------------------------------------------------------------
// TXk[b][(o*12+t)][m] = sum_f xTf[b][t][m][f] * ThT_k[o][f]   (MFMA, no LDS)
// A = xTf (M=m), B = ThT_k (N=o); D rows = m -> ushort4 stores along m.
// ---------------------------------------------------------------------------
__global__ __launch_bounds__(256) void k_thx(const u16* __restrict__ xTf,
                                             const u16* __restrict__ ThT_k,
                                             u16* __restrict__ TXk)
{
  int b = blockIdx.z, t = blockIdx.y, mh = blockIdx.x;
  int lane = threadIdx.x & 63, w = threadIdx.x >> 6;
  int l15 = lane & 15, h = lane >> 4;
  int mbase = mh * 512 + w * 128;
  const u16* xb = xTf + ((size_t)b * 12 + t) * Nn * 64;   // [m][f]
  u16* ob = TXk + ((size_t)b * CT + t) * Nn;              // + o*12*1024 + m

  v8s bfr[4][2];
#pragma unroll
  for (int nj = 0; nj < 4; ++nj)
#pragma unroll
    for (int kk = 0; kk < 2; ++kk)
      bfr[nj][kk] =
          *(const v8s*)(ThT_k + (nj * 16 + l15) * 64 + (kk * 4 + h) * 8);

#pragma unroll
  for (int mi = 0; mi < 8; ++mi) {
    int m = mbase + mi * 16;
    v8s a0 = *(const v8s*)(xb + (size_t)(m + l15) * 64 + h * 8);
    v8s a1 = *(const v8s*)(xb + (size_t)(m + l15) * 64 + 32 + h * 8);
#pragma unroll
    for (int nj = 0; nj < 4; ++nj) {
      v4f acc = {};
      acc = __builtin_amdgcn_mfma_f32_16x16x32_bf16(a0, bfr[nj][0], acc, 0, 0, 0);
      acc = __builtin_amdgcn_mfma_f32_16x16x32_bf16(a1, bfr[nj][1], acc, 0, 0, 0);
      int o = nj * 16 + l15;
      ushort4 st = make_ushort4(f2bf(acc[0]), f2bf(acc[1]), f2bf(acc[2]),
                                f2bf(acc[3]));
      *(ushort4*)(ob + (size_t)o * (12 * Nn) + m + h * 4) = st;
    }
  }
}

// ---------------------------------------------------------------------------
// K5: out[b,n,c'] (mode: =, +=, +=&relu) = AS_k[b,n,:] @ TXk[b,c',:]^T (MFMA)
// ---------------------------------------------------------------------------
__global__ __launch_bounds__(256) void k_gemm_out(
    const u16* __restrict__ ASk, const u16* __restrict__ TXk,
    float* __restrict__ out, int mode)
{
  __shared__ u16 As[8192];
  __shared__ u16 Bs[8192];
  const int tid = threadIdx.x;
  const int lane = tid & 63;
  const int w = tid >> 6, wr = w >> 1, wc = w & 1;
  const int b = blockIdx.z;
  const int n0 = blockIdx.y * 128;
  const int c0 = blockIdx.x * 128;
  const u16* Ag = ASk + ((size_t)b << 20);
  const u16* Bg = TXk + (size_t)b * CT * Nn;

  size_t aoff[4], boff[4];
  u16 *alds[4], *blds[4];
#pragma unroll
  for (int i = 0; i < 4; ++i) {
    int ch = (w * 4 + i) * 64 + lane;
    int row = ch >> 3;
    int kc = (ch & 7) ^ (row & 7);
    aoff[i] = (size_t)(n0 + row) * Nn + kc * 8;
    boff[i] = (size_t)(c0 + row) * Nn + kc * 8;
    alds[i] = (u16*)As + (size_t)(w * 4 + i) * 512;
    blds[i] = (u16*)Bs + (size_t)(w * 4 + i) * 512;
  }

  v4f acc[4][4] = {};
  const int l15 = lane & 15, h = lane >> 4;

  for (int k0 = 0; k0 < Nn; k0 += 64) {
    __syncthreads();
#pragma unroll
    for (int i = 0; i < 4; ++i) {
      gl_lds16(Ag + aoff[i] + k0, alds[i]);
      gl_lds16(Bg + boff[i] + k0, blds[i]);
    }
    __syncthreads();
#pragma unroll
    for (int kk = 0; kk < 2; ++kk) {
      v8s a[4], bf[4];
#pragma unroll
      for (int mi = 0; mi < 4; ++mi) {
        int rA = wr * 64 + mi * 16 + l15;
        a[mi] = *(const v8s*)((const u16*)As + rA * 64 +
                              (((kk * 4 + h) ^ (rA & 7)) * 8));
      }
#pragma unroll
      for (int nj = 0; nj < 4; ++nj) {
        int rB = wc * 64 + nj * 16 + l15;
        bf[nj] = *(const v8s*)((const u16*)Bs + rB * 64 +
                               (((kk * 4 + h) ^ (rB & 7)) * 8));
      }
#pragma unroll
      for (int mi = 0; mi < 4; ++mi)
#pragma unroll
        for (int nj = 0; nj < 4; ++nj)
          acc[mi][nj] = __builtin_amdgcn_mfma_f32_16x16x32_bf16(
              a[mi], bf[nj], acc[mi][nj], 0, 0, 0);
    }
  }
  float* ob = out + (size_t)b * Nn * CT;
#pragma unroll
  for (int mi = 0; mi < 4; ++mi) {
    int rown = n0 + wr * 64 + mi * 16 + h * 4;
#pragma unroll
    for (int nj = 0; nj < 4; ++nj) {
      int colc = c0 + wc * 64 + nj * 16 + l15;
#pragma unroll
      for (int r = 0; r < 4; ++r) {
        float* p = ob + (size_t)(rown + r) * CT + colc;
        float v = acc[mi][nj][r];
        if (mode == 0)      *p = v;
        else if (mode == 1) *p = *p + v;
        else                *p = fmaxf(*p + v, 0.f);
      }
    }
  }
}

// ---------------------------------------------------------------------------
extern "C" void kernel_launch(void* const* d_in, const int* in_sizes, int n_in,
                              void* d_out, int out_size, void* d_ws,
                              size_t ws_size, hipStream_t stream)
{
  const float* x     = (const float*)d_in[0];
  const float* W1    = (const float*)d_in[1];
  const float* W2    = (const float*)d_in[2];
  const float* W3    = (const float*)d_in[3];
  const float* bs    = (const float*)d_in[4];
  const float* Vs    = (const float*)d_in[5];
  const float* cheb  = (const float*)d_in[6];
  const float* Theta = (const float*)d_in[7];
  float* out = (float*)d_out;

  // ws layout (~179.5 MB):
  //  lhs 768KB | rhs 768KB | AS 96MB (slab0 = Pt alias; slabs1,2 = Spre alias)
  //  St 32MB | xTf 24MB | TXk 24MB | Vs16 2MB | ThT 24KB
  const size_t BNT = (size_t)Bn * Nn * Tn;
  char* w = (char*)d_ws;
  float* lhs  = (float*)w;                       w += BNT * 4;
  float* rhs  = (float*)w;                       w += BNT * 4;
  u16*   AS   = (u16*)w;                         // 96 MB (3 slabs of 32)
  u16*   Pt   = AS;                              // alias slab 0
  float* Spre = (float*)(w + ((size_t)32 << 20)); // alias slabs 1-2
  w += (size_t)96 << 20;
  u16*   St   = (u16*)w;                         w += (size_t)32 << 20;
  u16*   xTf  = (u16*)w;                         w += (size_t)Bn * 12 * Nn * 64 * 2;
  u16*   TXk  = (u16*)w;                         w += (size_t)Bn * CT * Nn * 2;
  u16*   Vs16 = (u16*)w;                         w += (size_t)Nn * Nn * 2;
  u16*   ThT  = (u16*)w;

  k_attn_lr<<<(Bn * Nn) / 4, 256, 0, stream>>>(x, W1, W2, W3, lhs, rhs);
  k_vs16<<<1024, 256, 0, stream>>>(Vs, Vs16);
  k_xtf<<<dim3(Nn / 32, Bn), 256, 0, stream>>>(x, xTf);
  k_prod<<<dim3(Nn / 16, Bn), 256, 0, stream>>>(lhs, rhs, bs, Pt);
  k_gemm_vsP<<<dim3(Nn / 128, Nn / 128, Bn), 256, 0, stream>>>(Vs16, Pt, Spre);
  k_soft<<<dim3(Nn / 4, Bn), 256, 0, stream>>>(Spre, St);
  k_tht<<<1, 256, 0, stream>>>(Theta, ThT);
  k_as3<<<dim3(Nn / 64, Nn / 64, Bn), 256, 0, stream>>>(cheb, St, AS);
  for (int k = 0; k < 3; ++k) {
    k_thx<<<dim3(2, 12, Bn), 256, 0, stream>>>(xTf, ThT + (size_t)k * 4096,
                                               TXk);
    k_gemm_out<<<dim3(CT / 128, Nn / 128, Bn), 256, 0, stream>>>(
        AS + ((size_t)(k * 16) << 20), TXk, out, k);
  }
}

// Round 4
// 505.415 us; speedup vs baseline: 3.6426x; 1.1446x over previous
//
#include <hip/hip_runtime.h>

// MAMGCN submodule: B=16, N=1024, F_IN=64, T=12, K=3, F_OUT=64
// R4: fuse the per-k output GEMMs into ONE K=3072 GEMM:
//   out[b,n,c] = relu( sum over kc=(k*1024+m) of AS[b,n,kc] * TX[b,c,kc] )
//   AS[b][n][k*1024+m] = cheb_k[m,n]*S[b,m,n]  (k_as3, one pass)
//   TX[b][c][k*1024+m] = sum_f x[b,m,f,t]*Theta_k[f,o], c=o*12+t (k_thx3)
// No out RMW, 1 launch, 48 K-steps (was 3 launches x 16 steps + 2 RMW passes).

typedef __attribute__((ext_vector_type(8))) short v8s;   // bf16x8 (4 VGPR)
typedef __attribute__((ext_vector_type(4))) float v4f;   // fp32x4 acc
typedef unsigned short u16;
typedef unsigned int u32;

#define Bn 16
#define Nn 1024
#define Tn 12
#define CT 768
#define KK 3072   // fused K = 3*1024

__device__ inline u16 f2bf(float f) {
  u32 u = __float_as_uint(f);
  return (u16)((u + 0x8000u) >> 16);
}
__device__ inline float bf2f(u16 h) { return __uint_as_float(((u32)h) << 16); }

__device__ inline void gl_lds16(const void* g, void* l) {
  __builtin_amdgcn_global_load_lds(
      (const __attribute__((address_space(1))) u32*)g,
      (__attribute__((address_space(3))) u32*)l, 16, 0, 0);
}

// ---------------------------------------------------------------------------
// K1: lhs[b,n,t'] = (sum_t x*W1) @ W2 ; rhs[b,n,t] = sum_f W3*x
// ---------------------------------------------------------------------------
__global__ __launch_bounds__(256) void k_attn_lr(
    const float* __restrict__ x, const float* __restrict__ W1,
    const float* __restrict__ W2, const float* __restrict__ W3,
    float* __restrict__ lhs, float* __restrict__ rhs)
{
  int bn   = blockIdx.x * 4 + (threadIdx.x >> 6);
  int lane = threadIdx.x & 63;                     // = f
  const float* xp = x + (size_t)bn * (64 * Tn) + lane * Tn;
  float4 v0 = *(const float4*)(xp);
  float4 v1 = *(const float4*)(xp + 4);
  float4 v2 = *(const float4*)(xp + 8);
  float xv[12] = {v0.x, v0.y, v0.z, v0.w, v1.x, v1.y, v1.z, v1.w,
                  v2.x, v2.y, v2.z, v2.w};
  float w3 = W3[lane];
  float tmp = 0.f;
#pragma unroll
  for (int t = 0; t < 12; ++t) tmp += xv[t] * W1[t];
#pragma unroll
  for (int t = 0; t < 12; ++t) {
    float v = tmp * W2[lane * 12 + t];
    float r = w3 * xv[t];
#pragma unroll
    for (int off = 32; off; off >>= 1) {
      v += __shfl_xor(v, off);
      r += __shfl_xor(r, off);
    }
    if (lane == t) {
      lhs[(size_t)bn * 12 + t] = v;
      rhs[(size_t)bn * 12 + t] = r;
    }
  }
}

// ---------------------------------------------------------------------------
// Vs -> bf16
// ---------------------------------------------------------------------------
__global__ __launch_bounds__(256) void k_vs16(const float* __restrict__ Vs,
                                              u16* __restrict__ V16)
{
  size_t i = (size_t)blockIdx.x * 256 + threadIdx.x;
  float4 v = *(const float4*)(Vs + i * 4);
  *(ushort4*)(V16 + i * 4) =
      make_ushort4(f2bf(v.x), f2bf(v.y), f2bf(v.z), f2bf(v.w));
}

// ---------------------------------------------------------------------------
// x[b,m,(f,t)] -> xTf[b][t][m][f] bf16 (t-major, f-contiguous)
// ---------------------------------------------------------------------------
__global__ __launch_bounds__(256) void k_xtf(const float* __restrict__ x,
                                             u16* __restrict__ xTf)
{
  __shared__ u16 xs[32][768];
  int b = blockIdx.y, m0 = blockIdx.x * 32;
  const float* xb = x + ((size_t)b * Nn + m0) * CT;
  int tid = threadIdx.x;
#pragma unroll
  for (int q = 0; q < 24; ++q) {
    int idx = (q * 256 + tid) * 4;
    int i = idx / 768, j = idx % 768;
    float4 v = *(const float4*)(xb + (size_t)i * CT + j);
    xs[i][j]     = f2bf(v.x);
    xs[i][j + 1] = f2bf(v.y);
    xs[i][j + 2] = f2bf(v.z);
    xs[i][j + 3] = f2bf(v.w);
  }
  __syncthreads();
#pragma unroll
  for (int q = 0; q < 24; ++q) {
    int flat = q * 256 + tid;
    int t = flat >> 9;
    int rem = flat & 511;
    int i = rem >> 4, fq = rem & 15;
    ushort4 o;
    o.x = xs[i][(fq * 4 + 0) * 12 + t];
    o.y = xs[i][(fq * 4 + 1) * 12 + t];
    o.z = xs[i][(fq * 4 + 2) * 12 + t];
    o.w = xs[i][(fq * 4 + 3) * 12 + t];
    *(ushort4*)(xTf + (((size_t)b * 12 + t) * Nn + m0 + i) * 64 + fq * 4) = o;
  }
}

// ---------------------------------------------------------------------------
// K2: Pt[b,c,m] = bf16(sigmoid(lhs[b,m,:].rhs[b,c,:] + bs[m,c]))
// ---------------------------------------------------------------------------
__global__ __launch_bounds__(256) void k_prod(
    const float* __restrict__ lhs, const float* __restrict__ rhs,
    const float* __restrict__ bs, u16* __restrict__ Pt)
{
  __shared__ float ls[1024][13];
  __shared__ float rs[16][12];
  int b = blockIdx.y, c0 = blockIdx.x * 16;
  int tid = threadIdx.x;
  const float* lb = lhs + (size_t)b * Nn * 12;
#pragma unroll
  for (int mq = 0; mq < 4; ++mq) {
    int m = mq * 256 + tid;
    const float* p = lb + (size_t)m * 12;
    float4 a0 = *(const float4*)p;
    float4 a1 = *(const float4*)(p + 4);
    float4 a2 = *(const float4*)(p + 8);
    ls[m][0] = a0.x; ls[m][1] = a0.y; ls[m][2]  = a0.z; ls[m][3]  = a0.w;
    ls[m][4] = a1.x; ls[m][5] = a1.y; ls[m][6]  = a1.z; ls[m][7]  = a1.w;
    ls[m][8] = a2.x; ls[m][9] = a2.y; ls[m][10] = a2.z; ls[m][11] = a2.w;
  }
  if (tid < 192) {
    int cc = tid / 12, tt = tid % 12;
    rs[cc][tt] = rhs[((size_t)b * Nn + c0 + cc) * 12 + tt];
  }
  __syncthreads();
  u16* Pb = Pt + ((size_t)b << 20);
#pragma unroll
  for (int mq = 0; mq < 4; ++mq) {
    int m = mq * 256 + tid;
    float l[12];
#pragma unroll
    for (int t = 0; t < 12; ++t) l[t] = ls[m][t];
#pragma unroll
    for (int cc = 0; cc < 16; ++cc) {
      float d = bs[(size_t)m * Nn + c0 + cc];
#pragma unroll
      for (int t = 0; t < 12; ++t) d += l[t] * rs[cc][t];
      float sg = 1.f / (1.f + __expf(-d));
      Pb[(size_t)(c0 + cc) * Nn + m] = f2bf(sg);
    }
  }
}

// ---------------------------------------------------------------------------
// K3: Spre[b,c,n'] (transposed store) = Vs16[n',m] @ Pt[b,c,m]^T  (MFMA)
// ---------------------------------------------------------------------------
__global__ __launch_bounds__(256) void k_gemm_vsP(
    const u16* __restrict__ A, const u16* __restrict__ Pt,
    float* __restrict__ Spre)
{
  __shared__ u16 As[8192];
  __shared__ u16 Bs[8192];
  const int tid = threadIdx.x;
  const int lane = tid & 63;
  const int w = tid >> 6, wr = w >> 1, wc = w & 1;
  const int b = blockIdx.z;
  const int n0 = blockIdx.y * 128;
  const int c0 = blockIdx.x * 128;
  const u16* Bg = Pt + ((size_t)b << 20);

  size_t aoff[4], boff[4];
  u16 *alds[4], *blds[4];
#pragma unroll
  for (int i = 0; i < 4; ++i) {
    int ch = (w * 4 + i) * 64 + lane;
    int row = ch >> 3;
    int kc = (ch & 7) ^ (row & 7);
    aoff[i] = (size_t)(n0 + row) * Nn + kc * 8;
    boff[i] = (size_t)(c0 + row) * Nn + kc * 8;
    alds[i] = (u16*)As + (size_t)(w * 4 + i) * 512;
    blds[i] = (u16*)Bs + (size_t)(w * 4 + i) * 512;
  }

  v4f acc[4][4] = {};
  const int l15 = lane & 15, h = lane >> 4;

  for (int k0 = 0; k0 < Nn; k0 += 64) {
    __syncthreads();
#pragma unroll
    for (int i = 0; i < 4; ++i) {
      gl_lds16(A + aoff[i] + k0, alds[i]);
      gl_lds16(Bg + boff[i] + k0, blds[i]);
    }
    __syncthreads();
#pragma unroll
    for (int kk = 0; kk < 2; ++kk) {
      v8s a[4], bf[4];
#pragma unroll
      for (int mi = 0; mi < 4; ++mi) {
        int rA = wr * 64 + mi * 16 + l15;
        a[mi] = *(const v8s*)((const u16*)As + rA * 64 +
                              (((kk * 4 + h) ^ (rA & 7)) * 8));
      }
#pragma unroll
      for (int nj = 0; nj < 4; ++nj) {
        int rB = wc * 64 + nj * 16 + l15;
        bf[nj] = *(const v8s*)((const u16*)Bs + rB * 64 +
                               (((kk * 4 + h) ^ (rB & 7)) * 8));
      }
#pragma unroll
      for (int mi = 0; mi < 4; ++mi)
#pragma unroll
        for (int nj = 0; nj < 4; ++nj)
          acc[mi][nj] = __builtin_amdgcn_mfma_f32_16x16x32_bf16(
              a[mi], bf[nj], acc[mi][nj], 0, 0, 0);
    }
  }
  float* Sp = Spre + ((size_t)b << 20);
#pragma unroll
  for (int mi = 0; mi < 4; ++mi) {
    int rown = n0 + wr * 64 + mi * 16 + h * 4;
#pragma unroll
    for (int nj = 0; nj < 4; ++nj) {
      int colc = c0 + wc * 64 + nj * 16 + l15;
      *(float4*)(Sp + (size_t)colc * Nn + rown) = *(float4*)&acc[mi][nj];
    }
  }
}

// ---------------------------------------------------------------------------
// K4: softmax over contiguous n' axis of Spre[b,c,:] -> St bf16. Wave/row.
// ---------------------------------------------------------------------------
__global__ __launch_bounds__(256) void k_soft(const float* __restrict__ Spre,
                                              u16* __restrict__ St)
{
  int wid = threadIdx.x >> 6, lane = threadIdx.x & 63;
  int row = blockIdx.x * 4 + wid;
  int b = blockIdx.y;
  const float* p = Spre + ((size_t)b << 20) + (size_t)row * Nn;
  float v[16];
#pragma unroll
  for (int q = 0; q < 4; ++q) {
    float4 t = *(const float4*)(p + q * 256 + lane * 4);
    v[q * 4 + 0] = t.x; v[q * 4 + 1] = t.y;
    v[q * 4 + 2] = t.z; v[q * 4 + 3] = t.w;
  }
  float M = v[0];
#pragma unroll
  for (int i = 1; i < 16; ++i) M = fmaxf(M, v[i]);
#pragma unroll
  for (int off = 32; off; off >>= 1) M = fmaxf(M, __shfl_xor(M, off));
  float s = 0.f;
#pragma unroll
  for (int i = 0; i < 16; ++i) { v[i] = __expf(v[i] - M); s += v[i]; }
#pragma unroll
  for (int off = 32; off; off >>= 1) s += __shfl_xor(s, off);
  float inv = 1.f / s;
  u16* o = St + ((size_t)b << 20) + (size_t)row * Nn;
#pragma unroll
  for (int q = 0; q < 4; ++q) {
    u32 w0 = (u32)f2bf(v[q * 4 + 0] * inv) | ((u32)f2bf(v[q * 4 + 1] * inv) << 16);
    u32 w1 = (u32)f2bf(v[q * 4 + 2] * inv) | ((u32)f2bf(v[q * 4 + 3] * inv) << 16);
    *(uint2*)(o + q * 256 + lane * 4) = make_uint2(w0, w1);
  }
}

// ---------------------------------------------------------------------------
// ThT[k*64+o][f] = bf16(Theta[k][f][o])
// ---------------------------------------------------------------------------
__global__ __launch_bounds__(256) void k_tht(const float* __restrict__ Theta,
                                             u16* __restrict__ ThT)
{
  int tid = threadIdx.x;
#pragma unroll
  for (int q = 0; q < 48; ++q) {
    int flat = q * 256 + tid;
    int ko = flat >> 6, f = flat & 63;
    int k = ko >> 6, o = ko & 63;
    ThT[flat] = f2bf(Theta[((size_t)k * 64 + f) * 64 + o]);
  }
}

// ---------------------------------------------------------------------------
// AS[b][n][k*1024+m] = bf16(cheb_k[m,n] * S[b,m,n]) for all 3 k, one pass.
// ---------------------------------------------------------------------------
__global__ __launch_bounds__(256) void k_as3(const float* __restrict__ cheb,
                                             const u16* __restrict__ St,
                                             u16* __restrict__ AS)
{
  __shared__ float ch[3][64][65];
  int b = blockIdx.z, m0 = blockIdx.y * 64, n0 = blockIdx.x * 64;
  int tid = threadIdx.x;
#pragma unroll
  for (int kk = 0; kk < 3; ++kk)
#pragma unroll
    for (int q = 0; q < 16; ++q) {
      int idx = q * 256 + tid;
      int i = idx >> 6, j = idx & 63;   // i: m-local, j: n-local
      ch[kk][i][j] =
          cheb[((size_t)kk << 20) + (size_t)(m0 + i) * Nn + n0 + j];
    }
  __syncthreads();
  const u16* Stb = St + ((size_t)b << 20);
#pragma unroll
  for (int q = 0; q < 16; ++q) {
    int idx = q * 256 + tid;
    int i = idx >> 6, j = idx & 63;     // i: n-local, j: m-local
    float s = bf2f(Stb[(size_t)(n0 + i) * Nn + m0 + j]);
    size_t base = ((size_t)b * Nn + n0 + i) * KK + m0 + j;
#pragma unroll
    for (int kk = 0; kk < 3; ++kk)
      AS[base + (size_t)kk * Nn] = f2bf(ch[kk][j][i] * s);
  }
}

// ---------------------------------------------------------------------------
// TX[b][(o*12+t)][k*1024+m] = sum_f xTf[b][t][m][f] * ThT_k[o][f]
// blockIdx.x: {mh in [0,2), k in [0,3)}. MFMA, operands straight from global.
// ---------------------------------------------------------------------------
__global__ __launch_bounds__(256) void k_thx3(const u16* __restrict__ xTf,
                                              const u16* __restrict__ ThT,
                                              u16* __restrict__ TX)
{
  int b = blockIdx.z, t = blockIdx.y;
  int mh = blockIdx.x & 1, kk = blockIdx.x >> 1;
  int lane = threadIdx.x & 63, w = threadIdx.x >> 6;
  int l15 = lane & 15, h = lane >> 4;
  int mbase = mh * 512 + w * 128;
  const u16* xb = xTf + ((size_t)b * 12 + t) * Nn * 64;       // [m][f]
  const u16* Tk = ThT + (size_t)kk * 4096;                    // [o][f]
  u16* ob = TX + ((size_t)b * CT + t) * KK + (size_t)kk * Nn; // + o*12*KK + m

  v8s bfr[4][2];
#pragma unroll
  for (int nj = 0; nj < 4; ++nj)
#pragma unroll
    for (int q = 0; q < 2; ++q)
      bfr[nj][q] = *(const v8s*)(Tk + (nj * 16 + l15) * 64 + (q * 4 + h) * 8);

#pragma unroll
  for (int mi = 0; mi < 8; ++mi) {
    int m = mbase + mi * 16;
    v8s a0 = *(const v8s*)(xb + (size_t)(m + l15) * 64 + h * 8);
    v8s a1 = *(const v8s*)(xb + (size_t)(m + l15) * 64 + 32 + h * 8);
#pragma unroll
    for (int nj = 0; nj < 4; ++nj) {
      v4f acc = {};
      acc = __builtin_amdgcn_mfma_f32_16x16x32_bf16(a0, bfr[nj][0], acc, 0, 0, 0);
      acc = __builtin_amdgcn_mfma_f32_16x16x32_bf16(a1, bfr[nj][1], acc, 0, 0, 0);
      int o = nj * 16 + l15;
      ushort4 st = make_ushort4(f2bf(acc[0]), f2bf(acc[1]), f2bf(acc[2]),
                                f2bf(acc[3]));
      *(ushort4*)(ob + (size_t)o * (12 * KK) + m + h * 4) = st;
    }
  }
}

// ---------------------------------------------------------------------------
// K5 fused: out[b,n,c] = relu( AS[b,n,:KK] . TX[b,c,:KK] )   (MFMA, K=3072)
// ---------------------------------------------------------------------------
__global__ __launch_bounds__(256) void k_gemm_out(
    const u16* __restrict__ AS, const u16* __restrict__ TX,
    float* __restrict__ out)
{
  __shared__ u16 As[8192];
  __shared__ u16 Bs[8192];
  const int tid = threadIdx.x;
  const int lane = tid & 63;
  const int w = tid >> 6, wr = w >> 1, wc = w & 1;
  const int b = blockIdx.z;
  const int n0 = blockIdx.y * 128;
  const int c0 = blockIdx.x * 128;
  const u16* Ag = AS + (size_t)b * Nn * KK;
  const u16* Bg = TX + (size_t)b * CT * KK;

  size_t aoff[4], boff[4];
  u16 *alds[4], *blds[4];
#pragma unroll
  for (int i = 0; i < 4; ++i) {
    int ch = (w * 4 + i) * 64 + lane;
    int row = ch >> 3;
    int kc = (ch & 7) ^ (row & 7);
    aoff[i] = (size_t)(n0 + row) * KK + kc * 8;
    boff[i] = (size_t)(c0 + row) * KK + kc * 8;
    alds[i] = (u16*)As + (size_t)(w * 4 + i) * 512;
    blds[i] = (u16*)Bs + (size_t)(w * 4 + i) * 512;
  }

  v4f acc[4][4] = {};
  const int l15 = lane & 15, h = lane >> 4;

  for (int k0 = 0; k0 < KK; k0 += 64) {
    __syncthreads();
#pragma unroll
    for (int i = 0; i < 4; ++i) {
      gl_lds16(Ag + aoff[i] + k0, alds[i]);
      gl_lds16(Bg + boff[i] + k0, blds[i]);
    }
    __syncthreads();
#pragma unroll
    for (int kk = 0; kk < 2; ++kk) {
      v8s a[4], bf[4];
#pragma unroll
      for (int mi = 0; mi < 4; ++mi) {
        int rA = wr * 64 + mi * 16 + l15;
        a[mi] = *(const v8s*)((const u16*)As + rA * 64 +
                              (((kk * 4 + h) ^ (rA & 7)) * 8));
      }
#pragma unroll
      for (int nj = 0; nj < 4; ++nj) {
        int rB = wc * 64 + nj * 16 + l15;
        bf[nj] = *(const v8s*)((const u16*)Bs + rB * 64 +
                               (((kk * 4 + h) ^ (rB & 7)) * 8));
      }
#pragma unroll
      for (int mi = 0; mi < 4; ++mi)
#pragma unroll
        for (int nj = 0; nj < 4; ++nj)
          acc[mi][nj] = __builtin_amdgcn_mfma_f32_16x16x32_bf16(
              a[mi], bf[nj], acc[mi][nj], 0, 0, 0);
    }
  }
  float* ob = out + (size_t)b * Nn * CT;
#pragma unroll
  for (int mi = 0; mi < 4; ++mi) {
    int rown = n0 + wr * 64 + mi * 16 + h * 4;
#pragma unroll
    for (int nj = 0; nj < 4; ++nj) {
      int colc = c0 + wc * 64 + nj * 16 + l15;
#pragma unroll
      for (int r = 0; r < 4; ++r)
        ob[(size_t)(rown + r) * CT + colc] = fmaxf(acc[mi][nj][r], 0.f);
    }
  }
}

// ---------------------------------------------------------------------------
extern "C" void kernel_launch(void* const* d_in, const int* in_sizes, int n_in,
                              void* d_out, int out_size, void* d_ws,
                              size_t ws_size, hipStream_t stream)
{
  const float* x     = (const float*)d_in[0];
  const float* W1    = (const float*)d_in[1];
  const float* W2    = (const float*)d_in[2];
  const float* W3    = (const float*)d_in[3];
  const float* bs    = (const float*)d_in[4];
  const float* Vs    = (const float*)d_in[5];
  const float* cheb  = (const float*)d_in[6];
  const float* Theta = (const float*)d_in[7];
  float* out = (float*)d_out;

  // ws (~227.5 MB): lhs|rhs 1.5MB | AS 96MB [b][n][3072]
  //   (alias: Pt = AS first 32MB, Spre = AS+32MB as fp32 64MB)
  // | St 32MB | xTf 24MB | TX 72MB [b][768][3072] | Vs16 2MB | ThT 24KB
  const size_t BNT = (size_t)Bn * Nn * Tn;
  char* w = (char*)d_ws;
  float* lhs  = (float*)w;                        w += BNT * 4;
  float* rhs  = (float*)w;                        w += BNT * 4;
  u16*   AS   = (u16*)w;
  u16*   Pt   = AS;                               // alias (dead before k_as3)
  float* Spre = (float*)(w + ((size_t)32 << 20)); // alias (dead before k_as3)
  w += (size_t)96 << 20;
  u16*   St   = (u16*)w;                          w += (size_t)32 << 20;
  u16*   xTf  = (u16*)w;                          w += (size_t)Bn * 12 * Nn * 64 * 2;
  u16*   TX   = (u16*)w;                          w += (size_t)Bn * CT * KK * 2;
  u16*   Vs16 = (u16*)w;                          w += (size_t)Nn * Nn * 2;
  u16*   ThT  = (u16*)w;

  k_attn_lr<<<(Bn * Nn) / 4, 256, 0, stream>>>(x, W1, W2, W3, lhs, rhs);
  k_vs16<<<1024, 256, 0, stream>>>(Vs, Vs16);
  k_xtf<<<dim3(Nn / 32, Bn), 256, 0, stream>>>(x, xTf);
  k_prod<<<dim3(Nn / 16, Bn), 256, 0, stream>>>(lhs, rhs, bs, Pt);
  k_gemm_vsP<<<dim3(Nn / 128, Nn / 128, Bn), 256, 0, stream>>>(Vs16, Pt, Spre);
  k_soft<<<dim3(Nn / 4, Bn), 256, 0, stream>>>(Spre, St);
  k_tht<<<1, 256, 0, stream>>>(Theta, ThT);
  k_thx3<<<dim3(6, 12, Bn), 256, 0, stream>>>(xTf, ThT, TX);
  k_as3<<<dim3(Nn / 64, Nn / 64, Bn), 256, 0, stream>>>(cheb, St, AS);
  k_gemm_out<<<dim3(CT / 128, Nn / 128, Bn), 256, 0, stream>>>(AS, TX, out);
}

// Round 6
// 469.919 us; speedup vs baseline: 3.9177x; 1.0755x over previous
//
#include <hip/hip_runtime.h>

// MAMGCN submodule: B=16, N=1024, F_IN=64, T=12, K=3, F_OUT=64
// R5 (resubmit — prior round hit GPUAcquisitionTimeout, change unmeasured):
// chunked-bijective XCD swizzle on both MFMA GEMMs (T1).
//   k_gemm_out: 768 blocks = 8 XCD-chunks x 96 (2 full b per XCD) -> panel
//   sharers co-resident on one XCD L2; K-slice working set <1MB << 4MB.
//   k_gemm_vsP: 1024 blocks = 8 x 128, same scheme.
// Everything else unchanged from R4.

typedef __attribute__((ext_vector_type(8))) short v8s;   // bf16x8 (4 VGPR)
typedef __attribute__((ext_vector_type(4))) float v4f;   // fp32x4 acc
typedef unsigned short u16;
typedef unsigned int u32;

#define Bn 16
#define Nn 1024
#define Tn 12
#define CT 768
#define KK 3072   // fused K = 3*1024

__device__ inline u16 f2bf(float f) {
  u32 u = __float_as_uint(f);
  return (u16)((u + 0x8000u) >> 16);
}
__device__ inline float bf2f(u16 h) { return __uint_as_float(((u32)h) << 16); }

__device__ inline void gl_lds16(const void* g, void* l) {
  __builtin_amdgcn_global_load_lds(
      (const __attribute__((address_space(1))) u32*)g,
      (__attribute__((address_space(3))) u32*)l, 16, 0, 0);
}

// ---------------------------------------------------------------------------
// K1: lhs[b,n,t'] = (sum_t x*W1) @ W2 ; rhs[b,n,t] = sum_f W3*x
// ---------------------------------------------------------------------------
__global__ __launch_bounds__(256) void k_attn_lr(
    const float* __restrict__ x, const float* __restrict__ W1,
    const float* __restrict__ W2, const float* __restrict__ W3,
    float* __restrict__ lhs, float* __restrict__ rhs)
{
  int bn   = blockIdx.x * 4 + (threadIdx.x >> 6);
  int lane = threadIdx.x & 63;                     // = f
  const float* xp = x + (size_t)bn * (64 * Tn) + lane * Tn;
  float4 v0 = *(const float4*)(xp);
  float4 v1 = *(const float4*)(xp + 4);
  float4 v2 = *(const float4*)(xp + 8);
  float xv[12] = {v0.x, v0.y, v0.z, v0.w, v1.x, v1.y, v1.z, v1.w,
                  v2.x, v2.y, v2.z, v2.w};
  float w3 = W3[lane];
  float tmp = 0.f;
#pragma unroll
  for (int t = 0; t < 12; ++t) tmp += xv[t] * W1[t];
#pragma unroll
  for (int t = 0; t < 12; ++t) {
    float v = tmp * W2[lane * 12 + t];
    float r = w3 * xv[t];
#pragma unroll
    for (int off = 32; off; off >>= 1) {
      v += __shfl_xor(v, off);
      r += __shfl_xor(r, off);
    }
    if (lane == t) {
      lhs[(size_t)bn * 12 + t] = v;
      rhs[(size_t)bn * 12 + t] = r;
    }
  }
}

// ---------------------------------------------------------------------------
// Vs -> bf16
// ---------------------------------------------------------------------------
__global__ __launch_bounds__(256) void k_vs16(const float* __restrict__ Vs,
                                              u16* __restrict__ V16)
{
  size_t i = (size_t)blockIdx.x * 256 + threadIdx.x;
  float4 v = *(const float4*)(Vs + i * 4);
  *(ushort4*)(V16 + i * 4) =
      make_ushort4(f2bf(v.x), f2bf(v.y), f2bf(v.z), f2bf(v.w));
}

// ---------------------------------------------------------------------------
// x[b,m,(f,t)] -> xTf[b][t][m][f] bf16 (t-major, f-contiguous)
// ---------------------------------------------------------------------------
__global__ __launch_bounds__(256) void k_xtf(const float* __restrict__ x,
                                             u16* __restrict__ xTf)
{
  __shared__ u16 xs[32][768];
  int b = blockIdx.y, m0 = blockIdx.x * 32;
  const float* xb = x + ((size_t)b * Nn + m0) * CT;
  int tid = threadIdx.x;
#pragma unroll
  for (int q = 0; q < 24; ++q) {
    int idx = (q * 256 + tid) * 4;
    int i = idx / 768, j = idx % 768;
    float4 v = *(const float4*)(xb + (size_t)i * CT + j);
    xs[i][j]     = f2bf(v.x);
    xs[i][j + 1] = f2bf(v.y);
    xs[i][j + 2] = f2bf(v.z);
    xs[i][j + 3] = f2bf(v.w);
  }
  __syncthreads();
#pragma unroll
  for (int q = 0; q < 24; ++q) {
    int flat = q * 256 + tid;
    int t = flat >> 9;
    int rem = flat & 511;
    int i = rem >> 4, fq = rem & 15;
    ushort4 o;
    o.x = xs[i][(fq * 4 + 0) * 12 + t];
    o.y = xs[i][(fq * 4 + 1) * 12 + t];
    o.z = xs[i][(fq * 4 + 2) * 12 + t];
    o.w = xs[i][(fq * 4 + 3) * 12 + t];
    *(ushort4*)(xTf + (((size_t)b * 12 + t) * Nn + m0 + i) * 64 + fq * 4) = o;
  }
}

// ---------------------------------------------------------------------------
// K2: Pt[b,c,m] = bf16(sigmoid(lhs[b,m,:].rhs[b,c,:] + bs[m,c]))
// ---------------------------------------------------------------------------
__global__ __launch_bounds__(256) void k_prod(
    const float* __restrict__ lhs, const float* __restrict__ rhs,
    const float* __restrict__ bs, u16* __restrict__ Pt)
{
  __shared__ float ls[1024][13];
  __shared__ float rs[16][12];
  int b = blockIdx.y, c0 = blockIdx.x * 16;
  int tid = threadIdx.x;
  const float* lb = lhs + (size_t)b * Nn * 12;
#pragma unroll
  for (int mq = 0; mq < 4; ++mq) {
    int m = mq * 256 + tid;
    const float* p = lb + (size_t)m * 12;
    float4 a0 = *(const float4*)p;
    float4 a1 = *(const float4*)(p + 4);
    float4 a2 = *(const float4*)(p + 8);
    ls[m][0] = a0.x; ls[m][1] = a0.y; ls[m][2]  = a0.z; ls[m][3]  = a0.w;
    ls[m][4] = a1.x; ls[m][5] = a1.y; ls[m][6]  = a1.z; ls[m][7]  = a1.w;
    ls[m][8] = a2.x; ls[m][9] = a2.y; ls[m][10] = a2.z; ls[m][11] = a2.w;
  }
  if (tid < 192) {
    int cc = tid / 12, tt = tid % 12;
    rs[cc][tt] = rhs[((size_t)b * Nn + c0 + cc) * 12 + tt];
  }
  __syncthreads();
  u16* Pb = Pt + ((size_t)b << 20);
#pragma unroll
  for (int mq = 0; mq < 4; ++mq) {
    int m = mq * 256 + tid;
    float l[12];
#pragma unroll
    for (int t = 0; t < 12; ++t) l[t] = ls[m][t];
#pragma unroll
    for (int cc = 0; cc < 16; ++cc) {
      float d = bs[(size_t)m * Nn + c0 + cc];
#pragma unroll
      for (int t = 0; t < 12; ++t) d += l[t] * rs[cc][t];
      float sg = 1.f / (1.f + __expf(-d));
      Pb[(size_t)(c0 + cc) * Nn + m] = f2bf(sg);
    }
  }
}

// ---------------------------------------------------------------------------
// K3: Spre[b,c,n'] (transposed store) = Vs16[n',m] @ Pt[b,c,m]^T  (MFMA)
// 1D grid 1024 = 8 XCD-chunks x 128 (2 b per chunk), c-fastest within b.
// ---------------------------------------------------------------------------
__global__ __launch_bounds__(256) void k_gemm_vsP(
    const u16* __restrict__ A, const u16* __restrict__ Pt,
    float* __restrict__ Spre)
{
  __shared__ u16 As[8192];
  __shared__ u16 Bs[8192];
  const int tid = threadIdx.x;
  const int lane = tid & 63;
  const int w = tid >> 6, wr = w >> 1, wc = w & 1;
  const int bi = blockIdx.x;
  const int L = (bi & 7) * 128 + (bi >> 3);   // chunked XCD remap (1024%8==0)
  const int b = L >> 6;
  const int rem = L & 63;
  const int n0 = (rem >> 3) * 128;
  const int c0 = (rem & 7) * 128;
  const u16* Bg = Pt + ((size_t)b << 20);

  size_t aoff[4], boff[4];
  u16 *alds[4], *blds[4];
#pragma unroll
  for (int i = 0; i < 4; ++i) {
    int ch = (w * 4 + i) * 64 + lane;
    int row = ch >> 3;
    int kc = (ch & 7) ^ (row & 7);
    aoff[i] = (size_t)(n0 + row) * Nn + kc * 8;
    boff[i] = (size_t)(c0 + row) * Nn + kc * 8;
    alds[i] = (u16*)As + (size_t)(w * 4 + i) * 512;
    blds[i] = (u16*)Bs + (size_t)(w * 4 + i) * 512;
  }

  v4f acc[4][4] = {};
  const int l15 = lane & 15, h = lane >> 4;

  for (int k0 = 0; k0 < Nn; k0 += 64) {
    __syncthreads();
#pragma unroll
    for (int i = 0; i < 4; ++i) {
      gl_lds16(A + aoff[i] + k0, alds[i]);
      gl_lds16(Bg + boff[i] + k0, blds[i]);
    }
    __syncthreads();
#pragma unroll
    for (int kk = 0; kk < 2; ++kk) {
      v8s a[4], bf[4];
#pragma unroll
      for (int mi = 0; mi < 4; ++mi) {
        int rA = wr * 64 + mi * 16 + l15;
        a[mi] = *(const v8s*)((const u16*)As + rA * 64 +
                              (((kk * 4 + h) ^ (rA & 7)) * 8));
      }
#pragma unroll
      for (int nj = 0; nj < 4; ++nj) {
        int rB = wc * 64 + nj * 16 + l15;
        bf[nj] = *(const v8s*)((const u16*)Bs + rB * 64 +
                               (((kk * 4 + h) ^ (rB & 7)) * 8));
      }
#pragma unroll
      for (int mi = 0; mi < 4; ++mi)
#pragma unroll
        for (int nj = 0; nj < 4; ++nj)
          acc[mi][nj] = __builtin_amdgcn_mfma_f32_16x16x32_bf16(
              a[mi], bf[nj], acc[mi][nj], 0, 0, 0);
    }
  }
  float* Sp = Spre + ((size_t)b << 20);
#pragma unroll
  for (int mi = 0; mi < 4; ++mi) {
    int rown = n0 + wr * 64 + mi * 16 + h * 4;
#pragma unroll
    for (int nj = 0; nj < 4; ++nj) {
      int colc = c0 + wc * 64 + nj * 16 + l15;
      *(float4*)(Sp + (size_t)colc * Nn + rown) = *(float4*)&acc[mi][nj];
    }
  }
}

// ---------------------------------------------------------------------------
// K4: softmax over contiguous n' axis of Spre[b,c,:] -> St bf16. Wave/row.
// ---------------------------------------------------------------------------
__global__ __launch_bounds__(256) void k_soft(const float* __restrict__ Spre,
                                              u16* __restrict__ St)
{
  int wid = threadIdx.x >> 6, lane = threadIdx.x & 63;
  int row = blockIdx.x * 4 + wid;
  int b = blockIdx.y;
  const float* p = Spre + ((size_t)b << 20) + (size_t)row * Nn;
  float v[16];
#pragma unroll
  for (int q = 0; q < 4; ++q) {
    float4 t = *(const float4*)(p + q * 256 + lane * 4);
    v[q * 4 + 0] = t.x; v[q * 4 + 1] = t.y;
    v[q * 4 + 2] = t.z; v[q * 4 + 3] = t.w;
  }
  float M = v[0];
#pragma unroll
  for (int i = 1; i < 16; ++i) M = fmaxf(M, v[i]);
#pragma unroll
  for (int off = 32; off; off >>= 1) M = fmaxf(M, __shfl_xor(M, off));
  float s = 0.f;
#pragma unroll
  for (int i = 0; i < 16; ++i) { v[i] = __expf(v[i] - M); s += v[i]; }
#pragma unroll
  for (int off = 32; off; off >>= 1) s += __shfl_xor(s, off);
  float inv = 1.f / s;
  u16* o = St + ((size_t)b << 20) + (size_t)row * Nn;
#pragma unroll
  for (int q = 0; q < 4; ++q) {
    u32 w0 = (u32)f2bf(v[q * 4 + 0] * inv) | ((u32)f2bf(v[q * 4 + 1] * inv) << 16);
    u32 w1 = (u32)f2bf(v[q * 4 + 2] * inv) | ((u32)f2bf(v[q * 4 + 3] * inv) << 16);
    *(uint2*)(o + q * 256 + lane * 4) = make_uint2(w0, w1);
  }
}

// ---------------------------------------------------------------------------
// ThT[k*64+o][f] = bf16(Theta[k][f][o])
// ---------------------------------------------------------------------------
__global__ __launch_bounds__(256) void k_tht(const float* __restrict__ Theta,
                                             u16* __restrict__ ThT)
{
  int tid = threadIdx.x;
#pragma unroll
  for (int q = 0; q < 48; ++q) {
    int flat = q * 256 + tid;
    int ko = flat >> 6, f = flat & 63;
    int k = ko >> 6, o = ko & 63;
    ThT[flat] = f2bf(Theta[((size_t)k * 64 + f) * 64 + o]);
  }
}

// ---------------------------------------------------------------------------
// AS[b][n][k*1024+m] = bf16(cheb_k[m,n] * S[b,m,n]) for all 3 k, one pass.
// ---------------------------------------------------------------------------
__global__ __launch_bounds__(256) void k_as3(const float* __restrict__ cheb,
                                             const u16* __restrict__ St,
                                             u16* __restrict__ AS)
{
  __shared__ float ch[3][64][65];
  int b = blockIdx.z, m0 = blockIdx.y * 64, n0 = blockIdx.x * 64;
  int tid = threadIdx.x;
#pragma unroll
  for (int kk = 0; kk < 3; ++kk)
#pragma unroll
    for (int q = 0; q < 16; ++q) {
      int idx = q * 256 + tid;
      int i = idx >> 6, j = idx & 63;   // i: m-local, j: n-local
      ch[kk][i][j] =
          cheb[((size_t)kk << 20) + (size_t)(m0 + i) * Nn + n0 + j];
    }
  __syncthreads();
  const u16* Stb = St + ((size_t)b << 20);
#pragma unroll
  for (int q = 0; q < 16; ++q) {
    int idx = q * 256 + tid;
    int i = idx >> 6, j = idx & 63;     // i: n-local, j: m-local
    float s = bf2f(Stb[(size_t)(n0 + i) * Nn + m0 + j]);
    size_t base = ((size_t)b * Nn + n0 + i) * KK + m0 + j;
#pragma unroll
    for (int kk = 0; kk < 3; ++kk)
      AS[base + (size_t)kk * Nn] = f2bf(ch[kk][j][i] * s);
  }
}

// ---------------------------------------------------------------------------
// TX[b][(o*12+t)][k*1024+m] = sum_f xTf[b][t][m][f] * ThT_k[o][f]
// ---------------------------------------------------------------------------
__global__ __launch_bounds__(256) void k_thx3(const u16* __restrict__ xTf,
                                              const u16* __restrict__ ThT,
                                              u16* __restrict__ TX)
{
  int b = blockIdx.z, t = blockIdx.y;
  int mh = blockIdx.x & 1, kk = blockIdx.x >> 1;
  int lane = threadIdx.x & 63, w = threadIdx.x >> 6;
  int l15 = lane & 15, h = lane >> 4;
  int mbase = mh * 512 + w * 128;
  const u16* xb = xTf + ((size_t)b * 12 + t) * Nn * 64;       // [m][f]
  const u16* Tk = ThT + (size_t)kk * 4096;                    // [o][f]
  u16* ob = TX + ((size_t)b * CT + t) * KK + (size_t)kk * Nn; // + o*12*KK + m

  v8s bfr[4][2];
#pragma unroll
  for (int nj = 0; nj < 4; ++nj)
#pragma unroll
    for (int q = 0; q < 2; ++q)
      bfr[nj][q] = *(const v8s*)(Tk + (nj * 16 + l15) * 64 + (q * 4 + h) * 8);

#pragma unroll
  for (int mi = 0; mi < 8; ++mi) {
    int m = mbase + mi * 16;
    v8s a0 = *(const v8s*)(xb + (size_t)(m + l15) * 64 + h * 8);
    v8s a1 = *(const v8s*)(xb + (size_t)(m + l15) * 64 + 32 + h * 8);
#pragma unroll
    for (int nj = 0; nj < 4; ++nj) {
      v4f acc = {};
      acc = __builtin_amdgcn_mfma_f32_16x16x32_bf16(a0, bfr[nj][0], acc, 0, 0, 0);
      acc = __builtin_amdgcn_mfma_f32_16x16x32_bf16(a1, bfr[nj][1], acc, 0, 0, 0);
      int o = nj * 16 + l15;
      ushort4 st = make_ushort4(f2bf(acc[0]), f2bf(acc[1]), f2bf(acc[2]),
                                f2bf(acc[3]));
      *(ushort4*)(ob + (size_t)o * (12 * KK) + m + h * 4) = st;
    }
  }
}

// ---------------------------------------------------------------------------
// K5 fused: out[b,n,c] = relu( AS[b,n,:KK] . TX[b,c,:KK] )   (MFMA, K=3072)
// 1D grid 768 = 8 XCD-chunks x 96 (2 full b per chunk), c-fastest within b.
// ---------------------------------------------------------------------------
__global__ __launch_bounds__(256) void k_gemm_out(
    const u16* __restrict__ AS, const u16* __restrict__ TX,
    float* __restrict__ out)
{
  __shared__ u16 As[8192];
  __shared__ u16 Bs[8192];
  const int tid = threadIdx.x;
  const int lane = tid & 63;
  const int w = tid >> 6, wr = w >> 1, wc = w & 1;
  const int bi = blockIdx.x;
  const int L = (bi & 7) * 96 + (bi >> 3);    // chunked XCD remap (768%8==0)
  const int b = L / 48;
  const int rem = L % 48;
  const int n0 = (rem / 6) * 128;
  const int c0 = (rem % 6) * 128;
  const u16* Ag = AS + (size_t)b * Nn * KK;
  const u16* Bg = TX + (size_t)b * CT * KK;

  size_t aoff[4], boff[4];
  u16 *alds[4], *blds[4];
#pragma unroll
  for (int i = 0; i < 4; ++i) {
    int ch = (w * 4 + i) * 64 + lane;
    int row = ch >> 3;
    int kc = (ch & 7) ^ (row & 7);
    aoff[i] = (size_t)(n0 + row) * KK + kc * 8;
    boff[i] = (size_t)(c0 + row) * KK + kc * 8;
    alds[i] = (u16*)As + (size_t)(w * 4 + i) * 512;
    blds[i] = (u16*)Bs + (size_t)(w * 4 + i) * 512;
  }

  v4f acc[4][4] = {};
  const int l15 = lane & 15, h = lane >> 4;

  for (int k0 = 0; k0 < KK; k0 += 64) {
    __syncthreads();
#pragma unroll
    for (int i = 0; i < 4; ++i) {
      gl_lds16(Ag + aoff[i] + k0, alds[i]);
      gl_lds16(Bg + boff[i] + k0, blds[i]);
    }
    __syncthreads();
#pragma unroll
    for (int kk = 0; kk < 2; ++kk) {
      v8s a[4], bf[4];
#pragma unroll
      for (int mi = 0; mi < 4; ++mi) {
        int rA = wr * 64 + mi * 16 + l15;
        a[mi] = *(const v8s*)((const u16*)As + rA * 64 +
                              (((kk * 4 + h) ^ (rA & 7)) * 8));
      }
#pragma unroll
      for (int nj = 0; nj < 4; ++nj) {
        int rB = wc * 64 + nj * 16 + l15;
        bf[nj] = *(const v8s*)((const u16*)Bs + rB * 64 +
                               (((kk * 4 + h) ^ (rB & 7)) * 8));
      }
#pragma unroll
      for (int mi = 0; mi < 4; ++mi)
#pragma unroll
        for (int nj = 0; nj < 4; ++nj)
          acc[mi][nj] = __builtin_amdgcn_mfma_f32_16x16x32_bf16(
              a[mi], bf[nj], acc[mi][nj], 0, 0, 0);
    }
  }
  float* ob = out + (size_t)b * Nn * CT;
#pragma unroll
  for (int mi = 0; mi < 4; ++mi) {
    int rown = n0 + wr * 64 + mi * 16 + h * 4;
#pragma unroll
    for (int nj = 0; nj < 4; ++nj) {
      int colc = c0 + wc * 64 + nj * 16 + l15;
#pragma unroll
      for (int r = 0; r < 4; ++r)
        ob[(size_t)(rown + r) * CT + colc] = fmaxf(acc[mi][nj][r], 0.f);
    }
  }
}

// ---------------------------------------------------------------------------
extern "C" void kernel_launch(void* const* d_in, const int* in_sizes, int n_in,
                              void* d_out, int out_size, void* d_ws,
                              size_t ws_size, hipStream_t stream)
{
  const float* x     = (const float*)d_in[0];
  const float* W1    = (const float*)d_in[1];
  const float* W2    = (const float*)d_in[2];
  const float* W3    = (const float*)d_in[3];
  const float* bs    = (const float*)d_in[4];
  const float* Vs    = (const float*)d_in[5];
  const float* cheb  = (const float*)d_in[6];
  const float* Theta = (const float*)d_in[7];
  float* out = (float*)d_out;

  // ws (~227.5 MB): lhs|rhs 1.5MB | AS 96MB [b][n][3072]
  //   (alias: Pt = AS first 32MB, Spre = AS+32MB as fp32 64MB)
  // | St 32MB | xTf 24MB | TX 72MB [b][768][3072] | Vs16 2MB | ThT 24KB
  const size_t BNT = (size_t)Bn * Nn * Tn;
  char* w = (char*)d_ws;
  float* lhs  = (float*)w;                        w += BNT * 4;
  float* rhs  = (float*)w;                        w += BNT * 4;
  u16*   AS   = (u16*)w;
  u16*   Pt   = AS;                               // alias (dead before k_as3)
  float* Spre = (float*)(w + ((size_t)32 << 20)); // alias (dead before k_as3)
  w += (size_t)96 << 20;
  u16*   St   = (u16*)w;                          w += (size_t)32 << 20;
  u16*   xTf  = (u16*)w;                          w += (size_t)Bn * 12 * Nn * 64 * 2;
  u16*   TX   = (u16*)w;                          w += (size_t)Bn * CT * KK * 2;
  u16*   Vs16 = (u16*)w;                          w += (size_t)Nn * Nn * 2;
  u16*   ThT  = (u16*)w;

  k_attn_lr<<<(Bn * Nn) / 4, 256, 0, stream>>>(x, W1, W2, W3, lhs, rhs);
  k_vs16<<<1024, 256, 0, stream>>>(Vs, Vs16);
  k_xtf<<<dim3(Nn / 32, Bn), 256, 0, stream>>>(x, xTf);
  k_prod<<<dim3(Nn / 16, Bn), 256, 0, stream>>>(lhs, rhs, bs, Pt);
  k_gemm_vsP<<<1024, 256, 0, stream>>>(Vs16, Pt, Spre);
  k_soft<<<dim3(Nn / 4, Bn), 256, 0, stream>>>(Spre, St);
  k_tht<<<1, 256, 0, stream>>>(Theta, ThT);
  k_thx3<<<dim3(6, 12, Bn), 256, 0, stream>>>(xTf, ThT, TX);
  k_as3<<<dim3(Nn / 64, Nn / 64, Bn), 256, 0, stream>>>(cheb, St, AS);
  k_gemm_out<<<768, 256, 0, stream>>>(AS, TX, out);
}

// Round 7
// 418.334 us; speedup vs baseline: 4.4008x; 1.1233x over previous
//
#include <hip/hip_runtime.h>

// MAMGCN submodule: B=16, N=1024, F_IN=64, T=12, K=3, F_OUT=64
// R7: counted-vmcnt deep-pipeline GEMMs (T3+T4+T5), 8 waves, BM=256, BK=64,
//     2-tile lookahead, raw s_barrier (no vmcnt(0) drain in main loop).
//   k_gemm_out8: 256x192 tile -> 4x4x16 = 256 blocks (1/CU), 7 loads/tile.
//   k_gemm_vsP8: 256x256 tile -> 4x4x16 = 256 blocks (1/CU), 8 loads/tile.
// XCD chunked remap (256=8x32) + XOR-swizzled LDS kept from R5/R6.

typedef __attribute__((ext_vector_type(8))) short v8s;   // bf16x8 (4 VGPR)
typedef __attribute__((ext_vector_type(4))) float v4f;   // fp32x4 acc
typedef unsigned short u16;
typedef unsigned int u32;

#define Bn 16
#define Nn 1024
#define Tn 12
#define CT 768
#define KK 3072   // fused K = 3*1024

__device__ inline u16 f2bf(float f) {
  u32 u = __float_as_uint(f);
  return (u16)((u + 0x8000u) >> 16);
}
__device__ inline float bf2f(u16 h) { return __uint_as_float(((u32)h) << 16); }

__device__ inline void gl_lds16(const void* g, void* l) {
  __builtin_amdgcn_global_load_lds(
      (const __attribute__((address_space(1))) u32*)g,
      (__attribute__((address_space(3))) u32*)l, 16, 0, 0);
}

// ---------------------------------------------------------------------------
// K1: lhs[b,n,t'] = (sum_t x*W1) @ W2 ; rhs[b,n,t] = sum_f W3*x
// ---------------------------------------------------------------------------
__global__ __launch_bounds__(256) void k_attn_lr(
    const float* __restrict__ x, const float* __restrict__ W1,
    const float* __restrict__ W2, const float* __restrict__ W3,
    float* __restrict__ lhs, float* __restrict__ rhs)
{
  int bn   = blockIdx.x * 4 + (threadIdx.x >> 6);
  int lane = threadIdx.x & 63;                     // = f
  const float* xp = x + (size_t)bn * (64 * Tn) + lane * Tn;
  float4 v0 = *(const float4*)(xp);
  float4 v1 = *(const float4*)(xp + 4);
  float4 v2 = *(const float4*)(xp + 8);
  float xv[12] = {v0.x, v0.y, v0.z, v0.w, v1.x, v1.y, v1.z, v1.w,
                  v2.x, v2.y, v2.z, v2.w};
  float w3 = W3[lane];
  float tmp = 0.f;
#pragma unroll
  for (int t = 0; t < 12; ++t) tmp += xv[t] * W1[t];
#pragma unroll
  for (int t = 0; t < 12; ++t) {
    float v = tmp * W2[lane * 12 + t];
    float r = w3 * xv[t];
#pragma unroll
    for (int off = 32; off; off >>= 1) {
      v += __shfl_xor(v, off);
      r += __shfl_xor(r, off);
    }
    if (lane == t) {
      lhs[(size_t)bn * 12 + t] = v;
      rhs[(size_t)bn * 12 + t] = r;
    }
  }
}

// ---------------------------------------------------------------------------
// Vs -> bf16
// ---------------------------------------------------------------------------
__global__ __launch_bounds__(256) void k_vs16(const float* __restrict__ Vs,
                                              u16* __restrict__ V16)
{
  size_t i = (size_t)blockIdx.x * 256 + threadIdx.x;
  float4 v = *(const float4*)(Vs + i * 4);
  *(ushort4*)(V16 + i * 4) =
      make_ushort4(f2bf(v.x), f2bf(v.y), f2bf(v.z), f2bf(v.w));
}

// ---------------------------------------------------------------------------
// x[b,m,(f,t)] -> xTf[b][t][m][f] bf16 (t-major, f-contiguous)
// ---------------------------------------------------------------------------
__global__ __launch_bounds__(256) void k_xtf(const float* __restrict__ x,
                                             u16* __restrict__ xTf)
{
  __shared__ u16 xs[32][768];
  int b = blockIdx.y, m0 = blockIdx.x * 32;
  const float* xb = x + ((size_t)b * Nn + m0) * CT;
  int tid = threadIdx.x;
#pragma unroll
  for (int q = 0; q < 24; ++q) {
    int idx = (q * 256 + tid) * 4;
    int i = idx / 768, j = idx % 768;
    float4 v = *(const float4*)(xb + (size_t)i * CT + j);
    xs[i][j]     = f2bf(v.x);
    xs[i][j + 1] = f2bf(v.y);
    xs[i][j + 2] = f2bf(v.z);
    xs[i][j + 3] = f2bf(v.w);
  }
  __syncthreads();
#pragma unroll
  for (int q = 0; q < 24; ++q) {
    int flat = q * 256 + tid;
    int t = flat >> 9;
    int rem = flat & 511;
    int i = rem >> 4, fq = rem & 15;
    ushort4 o;
    o.x = xs[i][(fq * 4 + 0) * 12 + t];
    o.y = xs[i][(fq * 4 + 1) * 12 + t];
    o.z = xs[i][(fq * 4 + 2) * 12 + t];
    o.w = xs[i][(fq * 4 + 3) * 12 + t];
    *(ushort4*)(xTf + (((size_t)b * 12 + t) * Nn + m0 + i) * 64 + fq * 4) = o;
  }
}

// ---------------------------------------------------------------------------
// K2: Pt[b,c,m] = bf16(sigmoid(lhs[b,m,:].rhs[b,c,:] + bs[m,c]))
// ---------------------------------------------------------------------------
__global__ __launch_bounds__(256) void k_prod(
    const float* __restrict__ lhs, const float* __restrict__ rhs,
    const float* __restrict__ bs, u16* __restrict__ Pt)
{
  __shared__ float ls[1024][13];
  __shared__ float rs[16][12];
  int b = blockIdx.y, c0 = blockIdx.x * 16;
  int tid = threadIdx.x;
  const float* lb = lhs + (size_t)b * Nn * 12;
#pragma unroll
  for (int mq = 0; mq < 4; ++mq) {
    int m = mq * 256 + tid;
    const float* p = lb + (size_t)m * 12;
    float4 a0 = *(const float4*)p;
    float4 a1 = *(const float4*)(p + 4);
    float4 a2 = *(const float4*)(p + 8);
    ls[m][0] = a0.x; ls[m][1] = a0.y; ls[m][2]  = a0.z; ls[m][3]  = a0.w;
    ls[m][4] = a1.x; ls[m][5] = a1.y; ls[m][6]  = a1.z; ls[m][7]  = a1.w;
    ls[m][8] = a2.x; ls[m][9] = a2.y; ls[m][10] = a2.z; ls[m][11] = a2.w;
  }
  if (tid < 192) {
    int cc = tid / 12, tt = tid % 12;
    rs[cc][tt] = rhs[((size_t)b * Nn + c0 + cc) * 12 + tt];
  }
  __syncthreads();
  u16* Pb = Pt + ((size_t)b << 20);
#pragma unroll
  for (int mq = 0; mq < 4; ++mq) {
    int m = mq * 256 + tid;
    float l[12];
#pragma unroll
    for (int t = 0; t < 12; ++t) l[t] = ls[m][t];
#pragma unroll
    for (int cc = 0; cc < 16; ++cc) {
      float d = bs[(size_t)m * Nn + c0 + cc];
#pragma unroll
      for (int t = 0; t < 12; ++t) d += l[t] * rs[cc][t];
      float sg = 1.f / (1.f + __expf(-d));
      Pb[(size_t)(c0 + cc) * Nn + m] = f2bf(sg);
    }
  }
}

// ---------------------------------------------------------------------------
// K3 (pipelined): Spre[b,c,n'] = Vs16[n',m] @ Pt[b,c,m]^T
// BM=256(n') x BN=256(c), BK=64, 8 waves (2x4), 2-buf, counted vmcnt.
// ---------------------------------------------------------------------------
__global__ __launch_bounds__(512, 2) void k_gemm_vsP8(
    const u16* __restrict__ A, const u16* __restrict__ Pt,
    float* __restrict__ Spre)
{
  extern __shared__ u16 smem[];
  u16* AsL = smem;           // 2 x 16384 u16 (64 KB)
  u16* BsL = smem + 32768;   // 2 x 16384 u16 (64 KB)
  const int tid = threadIdx.x;
  const int lane = tid & 63;
  const int w = tid >> 6;              // 0..7
  const int wr = w >> 2, wc = w & 3;   // 2 x 4 wave grid
  const int l15 = lane & 15, h = lane >> 4;

  const int bi = blockIdx.x;                   // 256 blocks = 8 XCD x 32
  const int L = (bi & 7) * 32 + (bi >> 3);
  const int b = L >> 4;
  const int rem = L & 15;
  const int n0 = (rem >> 2) * 256;
  const int c0 = (rem & 3) * 256;
  const u16* Ag = A;                           // [n'][m] stride Nn
  const u16* Bg = Pt + ((size_t)b << 20);      // [c][m]  stride Nn

  int aro[4], bro[4], akc[4], dst[4];
#pragma unroll
  for (int i = 0; i < 4; ++i) {
    int ch = i * 512 + tid;
    int row = ch >> 3;
    int kc = (ch & 7) ^ (row & 7);             // pre-swizzled source chunk
    aro[i] = n0 + row; bro[i] = c0 + row; akc[i] = kc;
    dst[i] = ch * 8;
  }

#define STAGE_V(t, buf) do {                                              \
    const u16* As_ = Ag + (size_t)(t) * 64;                               \
    const u16* Bs_ = Bg + (size_t)(t) * 64;                               \
    _Pragma("unroll")                                                     \
    for (int i_ = 0; i_ < 4; ++i_) {                                      \
      gl_lds16(As_ + (size_t)aro[i_] * Nn + akc[i_] * 8,                  \
               AsL + (buf) * 16384 + dst[i_]);                            \
      gl_lds16(Bs_ + (size_t)bro[i_] * Nn + akc[i_] * 8,                  \
               BsL + (buf) * 16384 + dst[i_]);                            \
    } } while (0)

  v4f acc[8][4] = {};
  STAGE_V(0, 0);                               // 8 loads in flight
  STAGE_V(1, 1);                               // 16 in flight

  const int NT = Nn / 64;                      // 16
  for (int t = 0; t < NT; ++t) {
    const int cur = t & 1;
    if (t < NT - 1) asm volatile("s_waitcnt vmcnt(8)" ::: "memory");
    else            asm volatile("s_waitcnt vmcnt(0)" ::: "memory");
    __builtin_amdgcn_s_barrier();
    const u16* Ab = AsL + cur * 16384;
    const u16* Bb = BsL + cur * 16384;
#pragma unroll
    for (int ks = 0; ks < 2; ++ks) {
      v8s a[8], bf[4];
#pragma unroll
      for (int mi = 0; mi < 8; ++mi) {
        int rA = wr * 128 + mi * 16 + l15;
        a[mi] = *(const v8s*)(Ab + rA * 64 + (((ks * 4 + h) ^ (rA & 7)) * 8));
      }
#pragma unroll
      for (int nj = 0; nj < 4; ++nj) {
        int rB = wc * 64 + nj * 16 + l15;
        bf[nj] = *(const v8s*)(Bb + rB * 64 + (((ks * 4 + h) ^ (rB & 7)) * 8));
      }
      __builtin_amdgcn_s_setprio(1);
#pragma unroll
      for (int mi = 0; mi < 8; ++mi)
#pragma unroll
        for (int nj = 0; nj < 4; ++nj)
          acc[mi][nj] = __builtin_amdgcn_mfma_f32_16x16x32_bf16(
              a[mi], bf[nj], acc[mi][nj], 0, 0, 0);
      __builtin_amdgcn_s_setprio(0);
    }
    asm volatile("s_waitcnt lgkmcnt(0)" ::: "memory");
    __builtin_amdgcn_s_barrier();
    if (t + 2 < NT) STAGE_V(t + 2, cur);       // loads span the barriers
  }
#undef STAGE_V

  float* Sp = Spre + ((size_t)b << 20);
#pragma unroll
  for (int mi = 0; mi < 8; ++mi) {
    int rown = n0 + wr * 128 + mi * 16 + h * 4;
#pragma unroll
    for (int nj = 0; nj < 4; ++nj) {
      int colc = c0 + wc * 64 + nj * 16 + l15;
      *(float4*)(Sp + (size_t)colc * Nn + rown) = *(float4*)&acc[mi][nj];
    }
  }
}

// ---------------------------------------------------------------------------
// K4: softmax over contiguous n' axis of Spre[b,c,:] -> St bf16. Wave/row.
// ---------------------------------------------------------------------------
__global__ __launch_bounds__(256) void k_soft(const float* __restrict__ Spre,
                                              u16* __restrict__ St)
{
  int wid = threadIdx.x >> 6, lane = threadIdx.x & 63;
  int row = blockIdx.x * 4 + wid;
  int b = blockIdx.y;
  const float* p = Spre + ((size_t)b << 20) + (size_t)row * Nn;
  float v[16];
#pragma unroll
  for (int q = 0; q < 4; ++q) {
    float4 t = *(const float4*)(p + q * 256 + lane * 4);
    v[q * 4 + 0] = t.x; v[q * 4 + 1] = t.y;
    v[q * 4 + 2] = t.z; v[q * 4 + 3] = t.w;
  }
  float M = v[0];
#pragma unroll
  for (int i = 1; i < 16; ++i) M = fmaxf(M, v[i]);
#pragma unroll
  for (int off = 32; off; off >>= 1) M = fmaxf(M, __shfl_xor(M, off));
  float s = 0.f;
#pragma unroll
  for (int i = 0; i < 16; ++i) { v[i] = __expf(v[i] - M); s += v[i]; }
#pragma unroll
  for (int off = 32; off; off >>= 1) s += __shfl_xor(s, off);
  float inv = 1.f / s;
  u16* o = St + ((size_t)b << 20) + (size_t)row * Nn;
#pragma unroll
  for (int q = 0; q < 4; ++q) {
    u32 w0 = (u32)f2bf(v[q * 4 + 0] * inv) | ((u32)f2bf(v[q * 4 + 1] * inv) << 16);
    u32 w1 = (u32)f2bf(v[q * 4 + 2] * inv) | ((u32)f2bf(v[q * 4 + 3] * inv) << 16);
    *(uint2*)(o + q * 256 + lane * 4) = make_uint2(w0, w1);
  }
}

// ---------------------------------------------------------------------------
// ThT[k*64+o][f] = bf16(Theta[k][f][o])
// ---------------------------------------------------------------------------
__global__ __launch_bounds__(256) void k_tht(const float* __restrict__ Theta,
                                             u16* __restrict__ ThT)
{
  int tid = threadIdx.x;
#pragma unroll
  for (int q = 0; q < 48; ++q) {
    int flat = q * 256 + tid;
    int ko = flat >> 6, f = flat & 63;
    int k = ko >> 6, o = ko & 63;
    ThT[flat] = f2bf(Theta[((size_t)k * 64 + f) * 64 + o]);
  }
}

// ---------------------------------------------------------------------------
// AS[b][n][k*1024+m] = bf16(cheb_k[m,n] * S[b,m,n]) for all 3 k, one pass.
// ---------------------------------------------------------------------------
__global__ __launch_bounds__(256) void k_as3(const float* __restrict__ cheb,
                                             const u16* __restrict__ St,
                                             u16* __restrict__ AS)
{
  __shared__ float ch[3][64][65];
  int b = blockIdx.z, m0 = blockIdx.y * 64, n0 = blockIdx.x * 64;
  int tid = threadIdx.x;
#pragma unroll
  for (int kk = 0; kk < 3; ++kk)
#pragma unroll
    for (int q = 0; q < 16; ++q) {
      int idx = q * 256 + tid;
      int i = idx >> 6, j = idx & 63;   // i: m-local, j: n-local
      ch[kk][i][j] =
          cheb[((size_t)kk << 20) + (size_t)(m0 + i) * Nn + n0 + j];
    }
  __syncthreads();
  const u16* Stb = St + ((size_t)b << 20);
#pragma unroll
  for (int q = 0; q < 16; ++q) {
    int idx = q * 256 + tid;
    int i = idx >> 6, j = idx & 63;     // i: n-local, j: m-local
    float s = bf2f(Stb[(size_t)(n0 + i) * Nn + m0 + j]);
    size_t base = ((size_t)b * Nn + n0 + i) * KK + m0 + j;
#pragma unroll
    for (int kk = 0; kk < 3; ++kk)
      AS[base + (size_t)kk * Nn] = f2bf(ch[kk][j][i] * s);
  }
}

// ---------------------------------------------------------------------------
// TX[b][(o*12+t)][k*1024+m] = sum_f xTf[b][t][m][f] * ThT_k[o][f]
// ---------------------------------------------------------------------------
__global__ __launch_bounds__(256) void k_thx3(const u16* __restrict__ xTf,
                                              const u16* __restrict__ ThT,
                                              u16* __restrict__ TX)
{
  int b = blockIdx.z, t = blockIdx.y;
  int mh = blockIdx.x & 1, kk = blockIdx.x >> 1;
  int lane = threadIdx.x & 63, w = threadIdx.x >> 6;
  int l15 = lane & 15, h = lane >> 4;
  int mbase = mh * 512 + w * 128;
  const u16* xb = xTf + ((size_t)b * 12 + t) * Nn * 64;       // [m][f]
  const u16* Tk = ThT + (size_t)kk * 4096;                    // [o][f]
  u16* ob = TX + ((size_t)b * CT + t) * KK + (size_t)kk * Nn; // + o*12*KK + m

  v8s bfr[4][2];
#pragma unroll
  for (int nj = 0; nj < 4; ++nj)
#pragma unroll
    for (int q = 0; q < 2; ++q)
      bfr[nj][q] = *(const v8s*)(Tk + (nj * 16 + l15) * 64 + (q * 4 + h) * 8);

#pragma unroll
  for (int mi = 0; mi < 8; ++mi) {
    int m = mbase + mi * 16;
    v8s a0 = *(const v8s*)(xb + (size_t)(m + l15) * 64 + h * 8);
    v8s a1 = *(const v8s*)(xb + (size_t)(m + l15) * 64 + 32 + h * 8);
#pragma unroll
    for (int nj = 0; nj < 4; ++nj) {
      v4f acc = {};
      acc = __builtin_amdgcn_mfma_f32_16x16x32_bf16(a0, bfr[nj][0], acc, 0, 0, 0);
      acc = __builtin_amdgcn_mfma_f32_16x16x32_bf16(a1, bfr[nj][1], acc, 0, 0, 0);
      int o = nj * 16 + l15;
      ushort4 st = make_ushort4(f2bf(acc[0]), f2bf(acc[1]), f2bf(acc[2]),
                                f2bf(acc[3]));
      *(ushort4*)(ob + (size_t)o * (12 * KK) + m + h * 4) = st;
    }
  }
}

// ---------------------------------------------------------------------------
// K5 (pipelined): out[b,n,c] = relu( AS[b,n,:KK] . TX[b,c,:KK] )
// BM=256(n) x BN=192(c), BK=64, 8 waves (2x4, per-wave 128x48), 7 loads/tile.
// ---------------------------------------------------------------------------
__global__ __launch_bounds__(512, 2) void k_gemm_out8(
    const u16* __restrict__ AS, const u16* __restrict__ TX,
    float* __restrict__ out)
{
  extern __shared__ u16 smem[];
  u16* AsL = smem;           // 2 x 16384 u16 (64 KB)
  u16* BsL = smem + 32768;   // 2 x 12288 u16 (48 KB)
  const int tid = threadIdx.x;
  const int lane = tid & 63;
  const int w = tid >> 6;
  const int wr = w >> 2, wc = w & 3;
  const int l15 = lane & 15, h = lane >> 4;

  const int bi = blockIdx.x;                   // 256 blocks = 8 XCD x 32
  const int L = (bi & 7) * 32 + (bi >> 3);
  const int b = L >> 4;
  const int rem = L & 15;
  const int n0 = (rem >> 2) * 256;             // 4 n-tiles of 256
  const int c0 = (rem & 3) * 192;              // 4 c-tiles of 192
  const u16* Ag = AS + (size_t)b * Nn * KK;    // [n][kc] stride KK
  const u16* Bg = TX + (size_t)b * CT * KK;    // [c][kc] stride KK

  int aro[4], akc[4], adst[4];
#pragma unroll
  for (int i = 0; i < 4; ++i) {
    int ch = i * 512 + tid;
    int row = ch >> 3;
    akc[i] = (ch & 7) ^ (row & 7);
    aro[i] = n0 + row;
    adst[i] = ch * 8;
  }
  int bro[3], bkc[3], bdst[3];
#pragma unroll
  for (int i = 0; i < 3; ++i) {
    int ch = i * 512 + tid;                    // 1536 chunks = 192 rows x 8
    int row = ch >> 3;
    bkc[i] = (ch & 7) ^ (row & 7);
    bro[i] = c0 + row;
    bdst[i] = ch * 8;
  }

#define STAGE_O(t, buf) do {                                              \
    const u16* As_ = Ag + (size_t)(t) * 64;                               \
    const u16* Bs_ = Bg + (size_t)(t) * 64;                               \
    _Pragma("unroll")                                                     \
    for (int i_ = 0; i_ < 4; ++i_)                                        \
      gl_lds16(As_ + (size_t)aro[i_] * KK + akc[i_] * 8,                  \
               AsL + (buf) * 16384 + adst[i_]);                           \
    _Pragma("unroll")                                                     \
    for (int i_ = 0; i_ < 3; ++i_)                                        \
      gl_lds16(Bs_ + (size_t)bro[i_] * KK + bkc[i_] * 8,                  \
               BsL + (buf) * 12288 + bdst[i_]);                           \
    } while (0)

  v4f acc[8][3] = {};
  STAGE_O(0, 0);                               // 7 in flight
  STAGE_O(1, 1);                               // 14 in flight

  const int NT = KK / 64;                      // 48
  for (int t = 0; t < NT; ++t) {
    const int cur = t & 1;
    if (t < NT - 1) asm volatile("s_waitcnt vmcnt(7)" ::: "memory");
    else            asm volatile("s_waitcnt vmcnt(0)" ::: "memory");
    __builtin_amdgcn_s_barrier();
    const u16* Ab = AsL + cur * 16384;
    const u16* Bb = BsL + cur * 12288;
#pragma unroll
    for (int ks = 0; ks < 2; ++ks) {
      v8s a[8], bf[3];
#pragma unroll
      for (int mi = 0; mi < 8; ++mi) {
        int rA = wr * 128 + mi * 16 + l15;
        a[mi] = *(const v8s*)(Ab + rA * 64 + (((ks * 4 + h) ^ (rA & 7)) * 8));
      }
#pragma unroll
      for (int nj = 0; nj < 3; ++nj) {
        int rB = wc * 48 + nj * 16 + l15;
        bf[nj] = *(const v8s*)(Bb + rB * 64 + (((ks * 4 + h) ^ (rB & 7)) * 8));
      }
      __builtin_amdgcn_s_setprio(1);
#pragma unroll
      for (int mi = 0; mi < 8; ++mi)
#pragma unroll
        for (int nj = 0; nj < 3; ++nj)
          acc[mi][nj] = __builtin_amdgcn_mfma_f32_16x16x32_bf16(
              a[mi], bf[nj], acc[mi][nj], 0, 0, 0);
      __builtin_amdgcn_s_setprio(0);
    }
    asm volatile("s_waitcnt lgkmcnt(0)" ::: "memory");
    __builtin_amdgcn_s_barrier();
    if (t + 2 < NT) STAGE_O(t + 2, cur);
  }
#undef STAGE_O

  float* ob = out + (size_t)b * Nn * CT;
#pragma unroll
  for (int mi = 0; mi < 8; ++mi) {
    int rown = n0 + wr * 128 + mi * 16 + h * 4;
#pragma unroll
    for (int nj = 0; nj < 3; ++nj) {
      int colc = c0 + wc * 48 + nj * 16 + l15;
#pragma unroll
      for (int r = 0; r < 4; ++r)
        ob[(size_t)(rown + r) * CT + colc] = fmaxf(acc[mi][nj][r], 0.f);
    }
  }
}

// ---------------------------------------------------------------------------
extern "C" void kernel_launch(void* const* d_in, const int* in_sizes, int n_in,
                              void* d_out, int out_size, void* d_ws,
                              size_t ws_size, hipStream_t stream)
{
  const float* x     = (const float*)d_in[0];
  const float* W1    = (const float*)d_in[1];
  const float* W2    = (const float*)d_in[2];
  const float* W3    = (const float*)d_in[3];
  const float* bs    = (const float*)d_in[4];
  const float* Vs    = (const float*)d_in[5];
  const float* cheb  = (const float*)d_in[6];
  const float* Theta = (const float*)d_in[7];
  float* out = (float*)d_out;

  // ws (~227.5 MB): lhs|rhs 1.5MB | AS 96MB [b][n][3072]
  //   (alias: Pt = AS first 32MB, Spre = AS+32MB as fp32 64MB)
  // | St 32MB | xTf 24MB | TX 72MB [b][768][3072] | Vs16 2MB | ThT 24KB
  const size_t BNT = (size_t)Bn * Nn * Tn;
  char* w = (char*)d_ws;
  float* lhs  = (float*)w;                        w += BNT * 4;
  float* rhs  = (float*)w;                        w += BNT * 4;
  u16*   AS   = (u16*)w;
  u16*   Pt   = AS;                               // alias (dead before k_as3)
  float* Spre = (float*)(w + ((size_t)32 << 20)); // alias (dead before k_as3)
  w += (size_t)96 << 20;
  u16*   St   = (u16*)w;                          w += (size_t)32 << 20;
  u16*   xTf  = (u16*)w;                          w += (size_t)Bn * 12 * Nn * 64 * 2;
  u16*   TX   = (u16*)w;                          w += (size_t)Bn * CT * KK * 2;
  u16*   Vs16 = (u16*)w;                          w += (size_t)Nn * Nn * 2;
  u16*   ThT  = (u16*)w;

  // allow >64KB dynamic LDS (idempotent, host-side, graph-capture safe)
  (void)hipFuncSetAttribute((const void*)k_gemm_vsP8,
                            hipFuncAttributeMaxDynamicSharedMemorySize, 131072);
  (void)hipFuncSetAttribute((const void*)k_gemm_out8,
                            hipFuncAttributeMaxDynamicSharedMemorySize, 114688);

  k_attn_lr<<<(Bn * Nn) / 4, 256, 0, stream>>>(x, W1, W2, W3, lhs, rhs);
  k_vs16<<<1024, 256, 0, stream>>>(Vs, Vs16);
  k_xtf<<<dim3(Nn / 32, Bn), 256, 0, stream>>>(x, xTf);
  k_prod<<<dim3(Nn / 16, Bn), 256, 0, stream>>>(lhs, rhs, bs, Pt);
  k_gemm_vsP8<<<256, 512, 131072, stream>>>(Vs16, Pt, Spre);
  k_soft<<<dim3(Nn / 4, Bn), 256, 0, stream>>>(Spre, St);
  k_tht<<<1, 256, 0, stream>>>(Theta, ThT);
  k_thx3<<<dim3(6, 12, Bn), 256, 0, stream>>>(xTf, ThT, TX);
  k_as3<<<dim3(Nn / 64, Nn / 64, Bn), 256, 0, stream>>>(cheb, St, AS);
  k_gemm_out8<<<256, 512, 114688, stream>>>(AS, TX, out);
}

// Round 8
// 376.597 us; speedup vs baseline: 4.8886x; 1.1108x over previous
//
#include <hip/hip_runtime.h>

// MAMGCN submodule: B=16, N=1024, F_IN=64, T=12, K=3, F_OUT=64
// R8: (1) k_gemm_out8: all-frag upfront ds_read + EARLY barrier + STAGE(t+2)
//     issued BEFORE the MFMA cluster (load window ~2 tiles >= HBM latency).
//     (2) k_xtf fused into k_attn_lr (x read once). (3) St eliminated:
//     k_chebT + k_soft_as3 write AS = chebT .* softmax(Spre) directly.
//     Workspace re-laid: AS standalone (no Spre alias race); TX aliases Spre.

typedef __attribute__((ext_vector_type(8))) short v8s;   // bf16x8 (4 VGPR)
typedef __attribute__((ext_vector_type(4))) float v4f;   // fp32x4 acc
typedef unsigned short u16;
typedef unsigned int u32;

#define Bn 16
#define Nn 1024
#define Tn 12
#define CT 768
#define KK 3072   // fused K = 3*1024

__device__ inline u16 f2bf(float f) {
  u32 u = __float_as_uint(f);
  return (u16)((u + 0x8000u) >> 16);
}
__device__ inline float bf2f(u16 h) { return __uint_as_float(((u32)h) << 16); }

__device__ inline void gl_lds16(const void* g, void* l) {
  __builtin_amdgcn_global_load_lds(
      (const __attribute__((address_space(1))) u32*)g,
      (__attribute__((address_space(3))) u32*)l, 16, 0, 0);
}

// ---------------------------------------------------------------------------
// K1 (fused): lhs[b,n,t'] = (sum_t x*W1)@W2 ; rhs[b,n,t] = sum_f W3*x ;
//             xTf[b][t][m][f] = bf16(x[b,m,f,t])  (written from same regs)
// ---------------------------------------------------------------------------
__global__ __launch_bounds__(256) void k_attn_lr(
    const float* __restrict__ x, const float* __restrict__ W1,
    const float* __restrict__ W2, const float* __restrict__ W3,
    float* __restrict__ lhs, float* __restrict__ rhs, u16* __restrict__ xTf)
{
  int bn   = blockIdx.x * 4 + (threadIdx.x >> 6);  // b*N + m
  int lane = threadIdx.x & 63;                     // = f
  const float* xp = x + (size_t)bn * (64 * Tn) + lane * Tn;
  float4 v0 = *(const float4*)(xp);
  float4 v1 = *(const float4*)(xp + 4);
  float4 v2 = *(const float4*)(xp + 8);
  float xv[12] = {v0.x, v0.y, v0.z, v0.w, v1.x, v1.y, v1.z, v1.w,
                  v2.x, v2.y, v2.z, v2.w};
  int b = bn >> 10, m = bn & 1023;
#pragma unroll
  for (int t = 0; t < 12; ++t)
    xTf[(((size_t)b * 12 + t) * Nn + m) * 64 + lane] = f2bf(xv[t]);

  float w3 = W3[lane];
  float tmp = 0.f;
#pragma unroll
  for (int t = 0; t < 12; ++t) tmp += xv[t] * W1[t];
#pragma unroll
  for (int t = 0; t < 12; ++t) {
    float v = tmp * W2[lane * 12 + t];
    float r = w3 * xv[t];
#pragma unroll
    for (int off = 32; off; off >>= 1) {
      v += __shfl_xor(v, off);
      r += __shfl_xor(r, off);
    }
    if (lane == t) {
      lhs[(size_t)bn * 12 + t] = v;
      rhs[(size_t)bn * 12 + t] = r;
    }
  }
}

// ---------------------------------------------------------------------------
// Vs -> bf16
// ---------------------------------------------------------------------------
__global__ __launch_bounds__(256) void k_vs16(const float* __restrict__ Vs,
                                              u16* __restrict__ V16)
{
  size_t i = (size_t)blockIdx.x * 256 + threadIdx.x;
  float4 v = *(const float4*)(Vs + i * 4);
  *(ushort4*)(V16 + i * 4) =
      make_ushort4(f2bf(v.x), f2bf(v.y), f2bf(v.z), f2bf(v.w));
}

// ---------------------------------------------------------------------------
// chebT[k][n][m] = cheb[k][m][n]  (fp32 tile transpose)
// ---------------------------------------------------------------------------
__global__ __launch_bounds__(256) void k_chebT(const float* __restrict__ cheb,
                                               float* __restrict__ chebT)
{
  __shared__ float tbuf[64][65];
  int k = blockIdx.z, m0 = blockIdx.y * 64, n0 = blockIdx.x * 64;
  const float* src = cheb + ((size_t)k << 20);
  float* dst = chebT + ((size_t)k << 20);
  int tid = threadIdx.x;
#pragma unroll
  for (int q = 0; q < 16; ++q) {
    int idx = q * 256 + tid;
    int i = idx >> 6, j = idx & 63;   // i: m-local, j: n-local
    tbuf[i][j] = src[(size_t)(m0 + i) * Nn + n0 + j];
  }
  __syncthreads();
#pragma unroll
  for (int q = 0; q < 16; ++q) {
    int idx = q * 256 + tid;
    int i = idx >> 6, j = idx & 63;   // i: n-local, j: m-local
    dst[(size_t)(n0 + i) * Nn + m0 + j] = tbuf[j][i];
  }
}

// ---------------------------------------------------------------------------
// K2: Pt[b,c,m] = bf16(sigmoid(lhs[b,m,:].rhs[b,c,:] + bs[m,c]))
// ---------------------------------------------------------------------------
__global__ __launch_bounds__(256) void k_prod(
    const float* __restrict__ lhs, const float* __restrict__ rhs,
    const float* __restrict__ bs, u16* __restrict__ Pt)
{
  __shared__ float ls[1024][13];
  __shared__ float rs[16][12];
  int b = blockIdx.y, c0 = blockIdx.x * 16;
  int tid = threadIdx.x;
  const float* lb = lhs + (size_t)b * Nn * 12;
#pragma unroll
  for (int mq = 0; mq < 4; ++mq) {
    int m = mq * 256 + tid;
    const float* p = lb + (size_t)m * 12;
    float4 a0 = *(const float4*)p;
    float4 a1 = *(const float4*)(p + 4);
    float4 a2 = *(const float4*)(p + 8);
    ls[m][0] = a0.x; ls[m][1] = a0.y; ls[m][2]  = a0.z; ls[m][3]  = a0.w;
    ls[m][4] = a1.x; ls[m][5] = a1.y; ls[m][6]  = a1.z; ls[m][7]  = a1.w;
    ls[m][8] = a2.x; ls[m][9] = a2.y; ls[m][10] = a2.z; ls[m][11] = a2.w;
  }
  if (tid < 192) {
    int cc = tid / 12, tt = tid % 12;
    rs[cc][tt] = rhs[((size_t)b * Nn + c0 + cc) * 12 + tt];
  }
  __syncthreads();
  u16* Pb = Pt + ((size_t)b << 20);
#pragma unroll
  for (int mq = 0; mq < 4; ++mq) {
    int m = mq * 256 + tid;
    float l[12];
#pragma unroll
    for (int t = 0; t < 12; ++t) l[t] = ls[m][t];
#pragma unroll
    for (int cc = 0; cc < 16; ++cc) {
      float d = bs[(size_t)m * Nn + c0 + cc];
#pragma unroll
      for (int t = 0; t < 12; ++t) d += l[t] * rs[cc][t];
      float sg = 1.f / (1.f + __expf(-d));
      Pb[(size_t)(c0 + cc) * Nn + m] = f2bf(sg);
    }
  }
}

// ---------------------------------------------------------------------------
// K3 (pipelined, R7 structure): Spre[b,c,n'] = Vs16[n',m] @ Pt[b,c,m]^T
// ---------------------------------------------------------------------------
__global__ __launch_bounds__(512, 2) void k_gemm_vsP8(
    const u16* __restrict__ A, const u16* __restrict__ Pt,
    float* __restrict__ Spre)
{
  extern __shared__ u16 smem[];
  u16* AsL = smem;           // 2 x 16384 u16 (64 KB)
  u16* BsL = smem + 32768;   // 2 x 16384 u16 (64 KB)
  const int tid = threadIdx.x;
  const int lane = tid & 63;
  const int w = tid >> 6;
  const int wr = w >> 2, wc = w & 3;
  const int l15 = lane & 15, h = lane >> 4;

  const int bi = blockIdx.x;                   // 256 blocks = 8 XCD x 32
  const int L = (bi & 7) * 32 + (bi >> 3);
  const int b = L >> 4;
  const int rem = L & 15;
  const int n0 = (rem >> 2) * 256;
  const int c0 = (rem & 3) * 256;
  const u16* Ag = A;
  const u16* Bg = Pt + ((size_t)b << 20);

  int aro[4], bro[4], akc[4], dst[4];
#pragma unroll
  for (int i = 0; i < 4; ++i) {
    int ch = i * 512 + tid;
    int row = ch >> 3;
    int kc = (ch & 7) ^ (row & 7);
    aro[i] = n0 + row; bro[i] = c0 + row; akc[i] = kc;
    dst[i] = ch * 8;
  }

#define STAGE_V(t, buf) do {                                              \
    const u16* As_ = Ag + (size_t)(t) * 64;                               \
    const u16* Bs_ = Bg + (size_t)(t) * 64;                               \
    _Pragma("unroll")                                                     \
    for (int i_ = 0; i_ < 4; ++i_) {                                      \
      gl_lds16(As_ + (size_t)aro[i_] * Nn + akc[i_] * 8,                  \
               AsL + (buf) * 16384 + dst[i_]);                            \
      gl_lds16(Bs_ + (size_t)bro[i_] * Nn + akc[i_] * 8,                  \
               BsL + (buf) * 16384 + dst[i_]);                            \
    } } while (0)

  v4f acc[8][4] = {};
  STAGE_V(0, 0);
  STAGE_V(1, 1);

  const int NT = Nn / 64;                      // 16
  for (int t = 0; t < NT; ++t) {
    const int cur = t & 1;
    if (t < NT - 1) asm volatile("s_waitcnt vmcnt(8)" ::: "memory");
    else            asm volatile("s_waitcnt vmcnt(0)" ::: "memory");
    __builtin_amdgcn_s_barrier();
    const u16* Ab = AsL + cur * 16384;
    const u16* Bb = BsL + cur * 16384;
#pragma unroll
    for (int ks = 0; ks < 2; ++ks) {
      v8s a[8], bf[4];
#pragma unroll
      for (int mi = 0; mi < 8; ++mi) {
        int rA = wr * 128 + mi * 16 + l15;
        a[mi] = *(const v8s*)(Ab + rA * 64 + (((ks * 4 + h) ^ (rA & 7)) * 8));
      }
#pragma unroll
      for (int nj = 0; nj < 4; ++nj) {
        int rB = wc * 64 + nj * 16 + l15;
        bf[nj] = *(const v8s*)(Bb + rB * 64 + (((ks * 4 + h) ^ (rB & 7)) * 8));
      }
      __builtin_amdgcn_s_setprio(1);
#pragma unroll
      for (int mi = 0; mi < 8; ++mi)
#pragma unroll
        for (int nj = 0; nj < 4; ++nj)
          acc[mi][nj] = __builtin_amdgcn_mfma_f32_16x16x32_bf16(
              a[mi], bf[nj], acc[mi][nj], 0, 0, 0);
      __builtin_amdgcn_s_setprio(0);
    }
    asm volatile("s_waitcnt lgkmcnt(0)" ::: "memory");
    __builtin_amdgcn_s_barrier();
    if (t + 2 < NT) STAGE_V(t + 2, cur);
  }
#undef STAGE_V

  float* Sp = Spre + ((size_t)b << 20);
#pragma unroll
  for (int mi = 0; mi < 8; ++mi) {
    int rown = n0 + wr * 128 + mi * 16 + h * 4;
#pragma unroll
    for (int nj = 0; nj < 4; ++nj) {
      int colc = c0 + wc * 64 + nj * 16 + l15;
      *(float4*)(Sp + (size_t)colc * Nn + rown) = *(float4*)&acc[mi][nj];
    }
  }
}

// ---------------------------------------------------------------------------
// K4 (fused): softmax over n' of Spre[b,c,:], then
//   AS[b][c][k*1024+m] = bf16( chebT[k][c][m] * soft[m] )   (St eliminated)
// ---------------------------------------------------------------------------
__global__ __launch_bounds__(256) void k_soft_as3(
    const float* __restrict__ Spre, const float* __restrict__ chebT,
    u16* __restrict__ AS)
{
  int wid = threadIdx.x >> 6, lane = threadIdx.x & 63;
  int row = blockIdx.x * 4 + wid;   // c (== output row n of AS)
  int b = blockIdx.y;
  const float* p = Spre + ((size_t)b << 20) + (size_t)row * Nn;
  float v[16];
#pragma unroll
  for (int q = 0; q < 4; ++q) {
    float4 t = *(const float4*)(p + q * 256 + lane * 4);
    v[q * 4 + 0] = t.x; v[q * 4 + 1] = t.y;
    v[q * 4 + 2] = t.z; v[q * 4 + 3] = t.w;
  }
  float M = v[0];
#pragma unroll
  for (int i = 1; i < 16; ++i) M = fmaxf(M, v[i]);
#pragma unroll
  for (int off = 32; off; off >>= 1) M = fmaxf(M, __shfl_xor(M, off));
  float s = 0.f;
#pragma unroll
  for (int i = 0; i < 16; ++i) { v[i] = __expf(v[i] - M); s += v[i]; }
#pragma unroll
  for (int off = 32; off; off >>= 1) s += __shfl_xor(s, off);
  float inv = 1.f / s;
  u16* o = AS + ((size_t)b * Nn + row) * KK;
#pragma unroll
  for (int kk = 0; kk < 3; ++kk) {
    const float* ct = chebT + ((size_t)kk << 20) + (size_t)row * Nn;
#pragma unroll
    for (int q = 0; q < 4; ++q) {
      int m = q * 256 + lane * 4;
      float4 cv = *(const float4*)(ct + m);
      ushort4 st = make_ushort4(f2bf(cv.x * v[q * 4 + 0] * inv),
                                f2bf(cv.y * v[q * 4 + 1] * inv),
                                f2bf(cv.z * v[q * 4 + 2] * inv),
                                f2bf(cv.w * v[q * 4 + 3] * inv));
      *(ushort4*)(o + kk * 1024 + m) = st;
    }
  }
}

// ---------------------------------------------------------------------------
// ThT[k*64+o][f] = bf16(Theta[k][f][o])
// ---------------------------------------------------------------------------
__global__ __launch_bounds__(256) void k_tht(const float* __restrict__ Theta,
                                             u16* __restrict__ ThT)
{
  int tid = threadIdx.x;
#pragma unroll
  for (int q = 0; q < 48; ++q) {
    int flat = q * 256 + tid;
    int ko = flat >> 6, f = flat & 63;
    int k = ko >> 6, o = ko & 63;
    ThT[flat] = f2bf(Theta[((size_t)k * 64 + f) * 64 + o]);
  }
}

// ---------------------------------------------------------------------------
// TX[b][(o*12+t)][k*1024+m] = sum_f xTf[b][t][m][f] * ThT_k[o][f]
// ---------------------------------------------------------------------------
__global__ __launch_bounds__(256) void k_thx3(const u16* __restrict__ xTf,
                                              const u16* __restrict__ ThT,
                                              u16* __restrict__ TX)
{
  int b = blockIdx.z, t = blockIdx.y;
  int mh = blockIdx.x & 1, kk = blockIdx.x >> 1;
  int lane = threadIdx.x & 63, w = threadIdx.x >> 6;
  int l15 = lane & 15, h = lane >> 4;
  int mbase = mh * 512 + w * 128;
  const u16* xb = xTf + ((size_t)b * 12 + t) * Nn * 64;       // [m][f]
  const u16* Tk = ThT + (size_t)kk * 4096;                    // [o][f]
  u16* ob = TX + ((size_t)b * CT + t) * KK + (size_t)kk * Nn; // + o*12*KK + m

  v8s bfr[4][2];
#pragma unroll
  for (int nj = 0; nj < 4; ++nj)
#pragma unroll
    for (int q = 0; q < 2; ++q)
      bfr[nj][q] = *(const v8s*)(Tk + (nj * 16 + l15) * 64 + (q * 4 + h) * 8);

#pragma unroll
  for (int mi = 0; mi < 8; ++mi) {
    int m = mbase + mi * 16;
    v8s a0 = *(const v8s*)(xb + (size_t)(m + l15) * 64 + h * 8);
    v8s a1 = *(const v8s*)(xb + (size_t)(m + l15) * 64 + 32 + h * 8);
#pragma unroll
    for (int nj = 0; nj < 4; ++nj) {
      v4f acc = {};
      acc = __builtin_amdgcn_mfma_f32_16x16x32_bf16(a0, bfr[nj][0], acc, 0, 0, 0);
      acc = __builtin_amdgcn_mfma_f32_16x16x32_bf16(a1, bfr[nj][1], acc, 0, 0, 0);
      int o = nj * 16 + l15;
      ushort4 st = make_ushort4(f2bf(acc[0]), f2bf(acc[1]), f2bf(acc[2]),
                                f2bf(acc[3]));
      *(ushort4*)(ob + (size_t)o * (12 * KK) + m + h * 4) = st;
    }
  }
}

// ---------------------------------------------------------------------------
// K5 (pipelined v2): out[b,n,c] = relu( AS[b,n,:KK] . TX[b,c,:KK] )
// All-frag upfront ds_read, early barrier, STAGE(t+2) issued BEFORE MFMA.
// ---------------------------------------------------------------------------
__global__ __launch_bounds__(512, 2) void k_gemm_out8(
    const u16* __restrict__ AS, const u16* __restrict__ TX,
    float* __restrict__ out)
{
  extern __shared__ u16 smem[];
  u16* AsL = smem;           // 2 x 16384 u16 (64 KB)
  u16* BsL = smem + 32768;   // 2 x 12288 u16 (48 KB)
  const int tid = threadIdx.x;
  const int lane = tid & 63;
  const int w = tid >> 6;
  const int wr = w >> 2, wc = w & 3;
  const int l15 = lane & 15, h = lane >> 4;

  const int bi = blockIdx.x;                   // 256 blocks = 8 XCD x 32
  const int L = (bi & 7) * 32 + (bi >> 3);
  const int b = L >> 4;
  const int rem = L & 15;
  const int n0 = (rem >> 2) * 256;
  const int c0 = (rem & 3) * 192;
  const u16* Ag = AS + (size_t)b * Nn * KK;
  const u16* Bg = TX + (size_t)b * CT * KK;

  int aro[4], akc[4], adst[4];
#pragma unroll
  for (int i = 0; i < 4; ++i) {
    int ch = i * 512 + tid;
    int row = ch >> 3;
    akc[i] = (ch & 7) ^ (row & 7);
    aro[i] = n0 + row;
    adst[i] = ch * 8;
  }
  int bro[3], bkc[3], bdst[3];
#pragma unroll
  for (int i = 0; i < 3; ++i) {
    int ch = i * 512 + tid;
    int row = ch >> 3;
    bkc[i] = (ch & 7) ^ (row & 7);
    bro[i] = c0 + row;
    bdst[i] = ch * 8;
  }

#define STAGE_O(t, buf) do {                                              \
    const u16* As_ = Ag + (size_t)(t) * 64;                               \
    const u16* Bs_ = Bg + (size_t)(t) * 64;                               \
    _Pragma("unroll")                                                     \
    for (int i_ = 0; i_ < 4; ++i_)                                        \
      gl_lds16(As_ + (size_t)aro[i_] * KK + akc[i_] * 8,                  \
               AsL + (buf) * 16384 + adst[i_]);                           \
    _Pragma("unroll")                                                     \
    for (int i_ = 0; i_ < 3; ++i_)                                        \
      gl_lds16(Bs_ + (size_t)bro[i_] * KK + bkc[i_] * 8,                  \
               BsL + (buf) * 12288 + bdst[i_]);                           \
    } while (0)

  v4f acc[8][3] = {};
  STAGE_O(0, 0);                               // 7 in flight
  STAGE_O(1, 1);                               // 14 in flight

  const int NT = KK / 64;                      // 48
  for (int t = 0; t < NT; ++t) {
    const int cur = t & 1;
    if (t < NT - 1) asm volatile("s_waitcnt vmcnt(7)" ::: "memory");
    else            asm volatile("s_waitcnt vmcnt(0)" ::: "memory");
    __builtin_amdgcn_s_barrier();
    const u16* Ab = AsL + cur * 16384;
    const u16* Bb = BsL + cur * 12288;
    // all fragments -> registers up front
    v8s a[2][8], bf[2][3];
#pragma unroll
    for (int ks = 0; ks < 2; ++ks) {
#pragma unroll
      for (int mi = 0; mi < 8; ++mi) {
        int rA = wr * 128 + mi * 16 + l15;
        a[ks][mi] =
            *(const v8s*)(Ab + rA * 64 + (((ks * 4 + h) ^ (rA & 7)) * 8));
      }
#pragma unroll
      for (int nj = 0; nj < 3; ++nj) {
        int rB = wc * 48 + nj * 16 + l15;
        bf[ks][nj] =
            *(const v8s*)(Bb + rB * 64 + (((ks * 4 + h) ^ (rB & 7)) * 8));
      }
    }
    asm volatile("s_waitcnt lgkmcnt(0)" ::: "memory");
    __builtin_amdgcn_s_barrier();               // all waves done with buf cur
    if (t + 2 < NT) STAGE_O(t + 2, cur);        // issue BEFORE compute:
    __builtin_amdgcn_s_setprio(1);              //   ~2-tile latency window
#pragma unroll
    for (int ks = 0; ks < 2; ++ks)
#pragma unroll
      for (int mi = 0; mi < 8; ++mi)
#pragma unroll
        for (int nj = 0; nj < 3; ++nj)
          acc[mi][nj] = __builtin_amdgcn_mfma_f32_16x16x32_bf16(
              a[ks][mi], bf[ks][nj], acc[mi][nj], 0, 0, 0);
    __builtin_amdgcn_s_setprio(0);
  }
#undef STAGE_O

  float* ob = out + (size_t)b * Nn * CT;
#pragma unroll
  for (int mi = 0; mi < 8; ++mi) {
    int rown = n0 + wr * 128 + mi * 16 + h * 4;
#pragma unroll
    for (int nj = 0; nj < 3; ++nj) {
      int colc = c0 + wc * 48 + nj * 16 + l15;
#pragma unroll
      for (int r = 0; r < 4; ++r)
        ob[(size_t)(rown + r) * CT + colc] = fmaxf(acc[mi][nj][r], 0.f);
    }
  }
}

// ---------------------------------------------------------------------------
extern "C" void kernel_launch(void* const* d_in, const int* in_sizes, int n_in,
                              void* d_out, int out_size, void* d_ws,
                              size_t ws_size, hipStream_t stream)
{
  const float* x     = (const float*)d_in[0];
  const float* W1    = (const float*)d_in[1];
  const float* W2    = (const float*)d_in[2];
  const float* W3    = (const float*)d_in[3];
  const float* bs    = (const float*)d_in[4];
  const float* Vs    = (const float*)d_in[5];
  const float* cheb  = (const float*)d_in[6];
  const float* Theta = (const float*)d_in[7];
  float* out = (float*)d_out;

  // ws (~208.1 MB), NO AS<->Spre alias (k_soft_as3 reads Spre, writes AS):
  //  [0,2)    lhs | rhs
  //  [2,98)   AS 96MB [b][n][3072]   (Pt aliases first 32MB — dead by then)
  //  [98,162) Spre 64MB fp32         (TX aliases [98,170) — Spre dead by then)
  //  [170,182) chebT 12MB fp32
  //  [182,206) xTf 24MB | [206,208) Vs16 | [208,..) ThT
  char* wsb = (char*)d_ws;
  const size_t MB = (size_t)1 << 20;
  float* lhs   = (float*)wsb;
  float* rhs   = lhs + (size_t)Bn * Nn * Tn;
  u16*   AS    = (u16*)(wsb + 2 * MB);
  u16*   Pt    = AS;                      // alias: dead before k_soft_as3
  float* Spre  = (float*)(wsb + 98 * MB);
  u16*   TX    = (u16*)(wsb + 98 * MB);   // alias: Spre dead before k_thx3
  float* chebT = (float*)(wsb + 170 * MB);
  u16*   xTf   = (u16*)(wsb + 182 * MB);
  u16*   Vs16  = (u16*)(wsb + 206 * MB);
  u16*   ThT   = (u16*)(wsb + 208 * MB);

  (void)hipFuncSetAttribute((const void*)k_gemm_vsP8,
                            hipFuncAttributeMaxDynamicSharedMemorySize, 131072);
  (void)hipFuncSetAttribute((const void*)k_gemm_out8,
                            hipFuncAttributeMaxDynamicSharedMemorySize, 114688);

  k_attn_lr<<<(Bn * Nn) / 4, 256, 0, stream>>>(x, W1, W2, W3, lhs, rhs, xTf);
  k_vs16<<<1024, 256, 0, stream>>>(Vs, Vs16);
  k_chebT<<<dim3(16, 16, 3), 256, 0, stream>>>(cheb, chebT);
  k_prod<<<dim3(Nn / 16, Bn), 256, 0, stream>>>(lhs, rhs, bs, Pt);
  k_gemm_vsP8<<<256, 512, 131072, stream>>>(Vs16, Pt, Spre);
  k_soft_as3<<<dim3(Nn / 4, Bn), 256, 0, stream>>>(Spre, chebT, AS);
  k_tht<<<1, 256, 0, stream>>>(Theta, ThT);
  k_thx3<<<dim3(6, 12, Bn), 256, 0, stream>>>(xTf, ThT, TX);
  k_gemm_out8<<<256, 512, 114688, stream>>>(AS, TX, out);
}